// Round 9
// baseline (243.998 us; speedup 1.0000x reference)
//
#include <hip/hip_runtime.h>
#include <math.h>

#define B_   8
#define T_   2048
#define NE_  384
#define HQ_  8
#define HKV_ 2
#define D_   48
#define DH_  24   // D/2

typedef __attribute__((ext_vector_type(8))) short bf16x8;
typedef __attribute__((ext_vector_type(4))) short bf16x4;
typedef __attribute__((ext_vector_type(4))) float f32x4;

static __device__ __forceinline__ short f2bf(float f) {
    union { float f; unsigned u; } v; v.f = f;
    unsigned r = (v.u + 0x7fffu + ((v.u >> 16) & 1u)) >> 16;
    return (short)r;
}

// native 2^x (scores are pre-scaled by log2(e) in the QKV epilogue)
static __device__ __forceinline__ float exp2_fast(float x) {
    float r;
    asm("v_exp_f32 %0, %1" : "=v"(r) : "v"(x));
    return r;
}
// packed f32x2 -> bf16x2 RNE conversion, one instruction
static __device__ __forceinline__ unsigned cvt_pk_bf16(float lo, float hi) {
    unsigned r;
    asm("v_cvt_pk_bf16_f32 %0, %1, %2" : "=v"(r) : "v"(lo), "v"(hi));
    return r;
}
static __device__ __forceinline__ float max3f(float a, float b, float c) {
    float r;
    asm("v_max3_f32 %0, %1, %2, %3" : "=v"(r) : "v"(a), "v"(b), "v"(c));
    return r;
}
// async global->LDS DMA, 16B per lane (dest = wave-uniform base + lane*16)
static __device__ __forceinline__ void gld16(const void* g, void* l) {
    __builtin_amdgcn_global_load_lds(
        (const __attribute__((address_space(1))) unsigned int*)g,
        (__attribute__((address_space(3))) unsigned int*)l,
        16, 0, 0);
}

// ---------------- kernel 0: prep (convert + transpose + rope table) --------
__global__ __launch_bounds__(256) void prep_kernel(
    const float* __restrict__ x, const float* __restrict__ wq,
    const float* __restrict__ wk, const float* __restrict__ wv,
    const float* __restrict__ wo,
    short* __restrict__ xb, short* __restrict__ wt, short* __restrict__ wot,
    float* __restrict__ ct, float* __restrict__ st)
{
    const int bid = blockIdx.x, tid = threadIdx.x;
    if (bid < 6144) {
        int i = bid * 256 + tid;                 // float4 index, 1572864 total
        float4 v = ((const float4*)x)[i];
        bf16x4 o = { f2bf(v.x), f2bf(v.y), f2bf(v.z), f2bf(v.w) };
        *(bf16x4*)&xb[(size_t)i * 4] = o;
    } else if (bid < 7008) {
        int e = (bid - 6144) * 256 + tid;        // < 221184
        int n = e / 384, k = e - n * 384;
        float s = (n < 384) ? wq[(size_t)k * 384 + n]
                : (n < 480) ? wk[(size_t)k * 96 + (n - 384)]
                            : wv[(size_t)k * 96 + (n - 480)];
        wt[e] = f2bf(s);
    } else if (bid < 7584) {
        int e = (bid - 7008) * 256 + tid;        // < 147456
        int n = e / 384, k = e - n * 384;
        wot[e] = f2bf(wo[(size_t)k * 384 + n]);
    } else {
        int i = (bid - 7584) * 256 + tid;        // < 49152
        int t = i / DH_, j = i - t * DH_;
        double inv = pow(10000.0, -(double)(2 * j) / (double)D_);
        double ang = (double)t * inv;
        ct[i] = (float)cos(ang);
        st[i] = (float)sin(ang);
    }
}

// ---------------- kernel 1: QKV MFMA GEMM + fused RoPE ----------
// BK=64 double-buffered LDS via global_load_lds; pre-swizzled global source,
// matching XOR-swizzled ds_read_b128. One __syncthreads per K-tile.
__global__ __launch_bounds__(256) void qkv_gemm_kernel(
    const short* __restrict__ xb, const short* __restrict__ wt,
    const float* __restrict__ ct, const float* __restrict__ st,
    short* __restrict__ qb, short* __restrict__ kb, short* __restrict__ vtb)
{
    __shared__ __align__(16) char ldsb[49152];   // 2 x (A 16KB + B 8KB)
    const int tid = threadIdx.x;
    const int n0 = blockIdx.x * 64;     // 9 tiles
    const int m0 = blockIdx.y * 128;    // 128 tiles
    const int lane = tid & 63, w = tid >> 6;
    const int c = lane & 15, u = lane >> 4;
    const int mo = (w & 1) * 64, no = (w >> 1) * 32;
    const int lrow = lane >> 3;                          // 0..7 within 1KB chunk
    const int lcol = (((lane & 7) ^ lrow) << 4);         // swizzled src byte in 128B row
    f32x4 acc[4][2] = {};

    auto stage = [&](int bsel, int t) {
        char* dst = ldsb + bsel * 24576;
        const char* Ag = (const char*)xb + (size_t)(m0 + w * 32 + lrow) * 768 + t * 128 + lcol;
#pragma unroll
        for (int p = 0; p < 4; ++p)
            gld16(Ag + p * 8 * 768, dst + w * 4096 + p * 1024);
        const char* Bg = (const char*)wt + (size_t)(n0 + w * 16 + lrow) * 768 + t * 128 + lcol;
#pragma unroll
        for (int p = 0; p < 2; ++p)
            gld16(Bg + p * 8 * 768, dst + 16384 + w * 2048 + p * 1024);
    };

    stage(0, 0);
    __syncthreads();
    int cur = 0;
#pragma unroll 1
    for (int t = 0; t < 6; ++t) {
        if (t < 5) stage(cur ^ 1, t + 1);
        const char* Ab = ldsb + cur * 24576;
        const char* Bb = Ab + 16384;
#pragma unroll
        for (int kk = 0; kk < 2; ++kk) {
            const int off = (kk * 64 + u * 16) ^ ((c & 7) << 4);
            bf16x8 af[4], bfr[2];
#pragma unroll
            for (int i = 0; i < 4; ++i)
                af[i] = *(const bf16x8*)(Ab + (mo + 16 * i + c) * 128 + off);
#pragma unroll
            for (int j = 0; j < 2; ++j)
                bfr[j] = *(const bf16x8*)(Bb + (no + 16 * j + c) * 128 + off);
#pragma unroll
            for (int i = 0; i < 4; ++i)
#pragma unroll
                for (int j = 0; j < 2; ++j)
                    acc[i][j] = __builtin_amdgcn_mfma_f32_16x16x32_bf16(af[i], bfr[j], acc[i][j], 0, 0, 0);
        }
        __syncthreads();
        cur ^= 1;
    }

    // 1/sqrt(48) * log2(e): scores land in log2 domain so attn can use raw v_exp_f32
    const float qscale = 0.14433756729740643f * 1.4426950408889634f;
#pragma unroll
    for (int i = 0; i < 4; ++i) {
#pragma unroll
        for (int j = 0; j < 2; ++j) {
            int n = n0 + no + 16 * j + c;        // region uniform per 16-wide subtile
            int mb = m0 + mo + 16 * i + 4 * u;
            int b = mb >> 11;
            int t0 = mb & 2047;
            if (n < 480) {                       // q or k: RoPE, 64-padded store
                int nn = (n < 384) ? n : n - 384;
                int h = nn / 48, d = nn - h * 48;
                int fi = d >> 1;
                float sgn = (d & 1) ? 1.0f : -1.0f;
                float scl = (n < 384) ? qscale : 1.0f;
                short* dst = (n < 384) ? qb : kb;
                size_t base = (n < 384)
                    ? ((size_t)(b * HQ_ + h) * T_ + t0) * 64 + d
                    : ((size_t)(b * HKV_ + h) * T_ + t0) * 64 + d;
#pragma unroll
                for (int r = 0; r < 4; ++r) {
                    float val = acc[i][j][r];
                    float part = __shfl_xor(val, 1);
                    float cs = ct[(t0 + r) * DH_ + fi], sn = st[(t0 + r) * DH_ + fi];
                    dst[base + (size_t)r * 64] = f2bf((val * cs + sgn * part * sn) * scl);
                }
            } else {                             // v: no rope, transposed store
                int nn = n - 480;
                int h = nn / 48, d = nn - h * 48;
                ushort4 pk;
                pk.x = (unsigned short)f2bf(acc[i][j][0]);
                pk.y = (unsigned short)f2bf(acc[i][j][1]);
                pk.z = (unsigned short)f2bf(acc[i][j][2]);
                pk.w = (unsigned short)f2bf(acc[i][j][3]);
                *(ushort4*)&vtb[((size_t)(b * HKV_ + h) * D_ + d) * T_ + t0] = pk;
            }
        }
    }
}

// ---------------- kernel 2: LDS-staged head-split MFMA flash attention -----
// R8 body (1 head/block, balanced qt-pairs, LDS staging) with
// __launch_bounds__(256, 3): cross-round evidence (R1/R4/R5/R8) shows
// occupancy is set by the ALLOCATOR's register budget (unified VGPR+AGPR),
// not the algorithm — at bounds(256,2) the compiler consumes ~2-waves'
// worth of regs even for the 1-head body. Cap total at 512/3=170 (1-head
// live state ~140 fits) -> 3 blocks/CU.
__global__ __launch_bounds__(256, 3) void attn_kernel(
    const short* __restrict__ qb, const short* __restrict__ kb,
    const short* __restrict__ vtb, short* __restrict__ aob)
{
    __shared__ __align__(16) short lds_s[14336];   // 2 x (8KB K + 6KB V)
    const int tid = threadIdx.x;
    const int x  = blockIdx.x;          // 0..15: qt = 31-x then qt = x
    const int hk = blockIdx.y >> 2;     // 0..1
    const int g  = blockIdx.y & 3;      // head within group
    const int h  = hk * 4 + g;
    const int b  = blockIdx.z;
    const int lane = tid & 63;
    const int w = tid >> 6;             // q-subtile: q rows 16w..16w+15
    const int c = lane & 15;
    const int u = lane >> 4;

    const char* kg = (const char*)kb  + (size_t)(b * HKV_ + hk) * T_ * 128;   // K rows 128B
    const char* vg = (const char*)vtb + (size_t)(b * HKV_ + hk) * D_ * T_ * 2; // V^T row stride 4096B

    // stage-side source swizzle: lane l fetches the data belonging at
    // phys offset l*16 after the (row&7)<<4 involution
    const int swz  = (lane ^ ((lane >> 3) & 7)) << 4;   // within 1KB chunk (8 rows)
    const int vrow = lane >> 3;                          // 0..7
    const int voff = swz & 127;                          // within-row byte pos

    // read-side swizzle
    const int mk  = (c & 7) << 4;
    const int okl = (u * 16) ^ mk;            // K d 0..31 fragment
    const int okh = (64 | (u * 16)) ^ mk;     // K d 32..63 fragment

    auto stage = [&](int bsel, int jt) {
        char* dst = (char*)lds_s + bsel * 14336;
        const char* kt = kg + (size_t)jt * 8192;
        gld16(kt + (2 * w) * 1024 + swz,     dst + (2 * w) * 1024);
        gld16(kt + (2 * w + 1) * 1024 + swz, dst + (2 * w + 1) * 1024);
        if (w < 3) {                           // V: 6 chunks (48 rows x 128B)
            const char* vt = vg + (size_t)jt * 128;
            gld16(vt + (size_t)(16 * w + vrow) * 4096 + voff,
                  dst + 8192 + (2 * w) * 1024);
            gld16(vt + (size_t)(16 * w + 8 + vrow) * 4096 + voff,
                  dst + 8192 + (2 * w + 1) * 1024);
        }
    };

#pragma unroll 1
    for (int ph = 0; ph < 2; ++ph) {
        const int qt = ph ? x : 31 - x;     // complementary pair: 33 iters total
        const short* qp = qb + ((size_t)(b * HQ_ + h) * T_ + qt * 64 + 16 * w + c) * 64;
        bf16x8 qf0 = *(const bf16x8*)(qp + 8 * u);          // d 0..31
        bf16x8 qf1 = *(const bf16x8*)(qp + 32 + 8 * u);     // d 32..63 (pad=0)

        float m_s = -1e30f;
        float l_s = 0.f;
        f32x4 o[3] = {};

        int cur = 0;
        stage(0, 0);
        __syncthreads();

#pragma unroll 1
        for (int jt = 0; jt <= qt; ++jt) {
            if (jt < qt) stage(cur ^ 1, jt + 1);   // prefetch next tile

            const bool diag = (jt == qt);
            const int mtmax = diag ? (w + 1) : 4;
            const char* kbuf = (const char*)lds_s + cur * 14336;
            const char* vbuf = kbuf + 8192;

            bf16x8 klo[4], khi[4];
            bf16x4 vf[3][4];
#pragma unroll
            for (int mt = 0; mt < 4; ++mt) {
                if (mt < mtmax) {
                    klo[mt] = *(const bf16x8*)(kbuf + mt * 2048 + c * 128 + okl);
                    khi[mt] = *(const bf16x8*)(kbuf + mt * 2048 + c * 128 + okh);
                }
            }
#pragma unroll
            for (int nt = 0; nt < 3; ++nt)
#pragma unroll
                for (int k2 = 0; k2 < 4; ++k2)
                    if (k2 < mtmax)
                        vf[nt][k2] = *(const bf16x4*)(vbuf + nt * 2048 + c * 128 +
                                                      (((k2 * 32) | (u * 8)) ^ mk));

            // S^T tiles: s[mt] = S^T[k=16mt+4u+r][q=16w+c]  (log2 domain)
            f32x4 s[4];
            __builtin_amdgcn_s_setprio(1);
#pragma unroll
            for (int mt = 0; mt < 4; ++mt) {
                if (mt < mtmax) {
                    f32x4 a = {0.f, 0.f, 0.f, 0.f};
                    a = __builtin_amdgcn_mfma_f32_16x16x32_bf16(klo[mt], qf0, a, 0, 0, 0);
                    a = __builtin_amdgcn_mfma_f32_16x16x32_bf16(khi[mt], qf1, a, 0, 0, 0);
                    if (diag && mt == mtmax - 1) {      // diagonal 16x16 tile
#pragma unroll
                        for (int r = 0; r < 4; ++r)
                            a[r] = (4 * u + r > c) ? -1e30f : a[r];
                    }
                    s[mt] = a;
                }
            }
            __builtin_amdgcn_s_setprio(0);

            float mloc = -1e30f;
#pragma unroll
            for (int mt = 0; mt < 4; ++mt)
                if (mt < mtmax)
                    mloc = max3f(max3f(s[mt][0], s[mt][1], s[mt][2]), s[mt][3], mloc);
            mloc = fmaxf(mloc, __shfl_xor(mloc, 16));
            mloc = fmaxf(mloc, __shfl_xor(mloc, 32));   // per-q max (replicated over u)

            // T13 defer-max: rescale only when max grew by >8 (log2) => P <= 256
            if (__any(mloc > m_s + 8.0f)) {
                float mnew = fmaxf(m_s, mloc);
                float alpha = exp2_fast(m_s - mnew);
                m_s = mnew;
                l_s *= alpha;
                float a0 = __shfl(alpha, 4 * u + 0);
                float a1 = __shfl(alpha, 4 * u + 1);
                float a2 = __shfl(alpha, 4 * u + 2);
                float a3 = __shfl(alpha, 4 * u + 3);
#pragma unroll
                for (int nt = 0; nt < 3; ++nt) {
                    o[nt][0] *= a0; o[nt][1] *= a1;
                    o[nt][2] *= a2; o[nt][3] *= a3;
                }
            }

            float psum = 0.0f;
            bf16x4 pf[4];
#pragma unroll
            for (int mt = 0; mt < 4; ++mt) {
                if (mt < mtmax) {
                    float p0 = exp2_fast(s[mt][0] - m_s);
                    float p1 = exp2_fast(s[mt][1] - m_s);
                    float p2 = exp2_fast(s[mt][2] - m_s);
                    float p3 = exp2_fast(s[mt][3] - m_s);
                    psum += (p0 + p1) + (p2 + p3);
                    union { unsigned u2[2]; bf16x4 v; } pk;
                    pk.u2[0] = cvt_pk_bf16(p0, p1);
                    pk.u2[1] = cvt_pk_bf16(p2, p3);
                    pf[mt] = pk.v;
                }
            }
            psum += __shfl_xor(psum, 16);
            psum += __shfl_xor(psum, 32);
            l_s += psum;

            __builtin_amdgcn_s_setprio(1);
#pragma unroll
            for (int k2 = 0; k2 < 4; ++k2) {
                if (k2 < mtmax) {
#pragma unroll
                    for (int nt = 0; nt < 3; ++nt)
                        o[nt] = __builtin_amdgcn_mfma_f32_16x16x16bf16_1k(
                            pf[k2], vf[nt][k2], o[nt], 0, 0, 0);
                }
            }
            __builtin_amdgcn_s_setprio(0);

            __syncthreads();        // vmcnt-drain (stage done) + buffer handoff
            cur ^= 1;
        }

        // epilogue: O rows 16w+4u+r, cols 16nt+c
        float li = 1.0f / l_s;
        float l0 = __shfl(li, 4 * u + 0);
        float l1 = __shfl(li, 4 * u + 1);
        float l2 = __shfl(li, 4 * u + 2);
        float l3 = __shfl(li, 4 * u + 3);
        float lr[4] = { l0, l1, l2, l3 };
#pragma unroll
        for (int nt = 0; nt < 3; ++nt)
#pragma unroll
            for (int r = 0; r < 4; ++r) {
                int t = qt * 64 + 16 * w + 4 * u + r;
                aob[((size_t)b * T_ + t) * NE_ + h * D_ + 16 * nt + c] =
                    f2bf(o[nt][r] * lr[r]);
            }
    }
}

// ---------------- kernel 3: out projection MFMA + bias ----------------
// Same BK=64 gld16 double-buffer structure as qkv_gemm.
__global__ __launch_bounds__(256) void out_gemm_kernel(
    const short* __restrict__ aob, const short* __restrict__ wot,
    const float* __restrict__ bias, float* __restrict__ out)
{
    __shared__ __align__(16) char ldsb[49152];
    const int tid = threadIdx.x;
    const int n0 = blockIdx.x * 64;     // 6 tiles
    const int m0 = blockIdx.y * 128;    // 128 tiles
    const int lane = tid & 63, w = tid >> 6;
    const int c = lane & 15, u = lane >> 4;
    const int mo = (w & 1) * 64, no = (w >> 1) * 32;
    const int lrow = lane >> 3;
    const int lcol = (((lane & 7) ^ lrow) << 4);
    f32x4 acc[4][2] = {};

    auto stage = [&](int bsel, int t) {
        char* dst = ldsb + bsel * 24576;
        const char* Ag = (const char*)aob + (size_t)(m0 + w * 32 + lrow) * 768 + t * 128 + lcol;
#pragma unroll
        for (int p = 0; p < 4; ++p)
            gld16(Ag + p * 8 * 768, dst + w * 4096 + p * 1024);
        const char* Bg = (const char*)wot + (size_t)(n0 + w * 16 + lrow) * 768 + t * 128 + lcol;
#pragma unroll
        for (int p = 0; p < 2; ++p)
            gld16(Bg + p * 8 * 768, dst + 16384 + w * 2048 + p * 1024);
    };

    stage(0, 0);
    __syncthreads();
    int cur = 0;
#pragma unroll 1
    for (int t = 0; t < 6; ++t) {
        if (t < 5) stage(cur ^ 1, t + 1);
        const char* Ab = ldsb + cur * 24576;
        const char* Bb = Ab + 16384;
#pragma unroll
        for (int kk = 0; kk < 2; ++kk) {
            const int off = (kk * 64 + u * 16) ^ ((c & 7) << 4);
            bf16x8 af[4], bfr[2];
#pragma unroll
            for (int i = 0; i < 4; ++i)
                af[i] = *(const bf16x8*)(Ab + (mo + 16 * i + c) * 128 + off);
#pragma unroll
            for (int j = 0; j < 2; ++j)
                bfr[j] = *(const bf16x8*)(Bb + (no + 16 * j + c) * 128 + off);
#pragma unroll
            for (int i = 0; i < 4; ++i)
#pragma unroll
                for (int j = 0; j < 2; ++j)
                    acc[i][j] = __builtin_amdgcn_mfma_f32_16x16x32_bf16(af[i], bfr[j], acc[i][j], 0, 0, 0);
        }
        __syncthreads();
        cur ^= 1;
    }

#pragma unroll
    for (int i = 0; i < 4; ++i) {
#pragma unroll
        for (int j = 0; j < 2; ++j) {
            int n = n0 + no + 16 * j + c;
            int mb = m0 + mo + 16 * i + 4 * u;
            float bv = bias[n];
#pragma unroll
            for (int r = 0; r < 4; ++r)
                out[(size_t)(mb + r) * 384 + n] = acc[i][j][r] + bv;
        }
    }
}

// ---------------- launcher ----------------
extern "C" void kernel_launch(void* const* d_in, const int* in_sizes, int n_in,
                              void* d_out, int out_size, void* d_ws, size_t ws_size,
                              hipStream_t stream) {
    const float* x  = (const float*)d_in[0];
    const float* wq = (const float*)d_in[1];
    const float* wk = (const float*)d_in[2];
    const float* wv = (const float*)d_in[3];
    const float* wo = (const float*)d_in[4];
    const float* bo = (const float*)d_in[5];
    float* out = (float*)d_out;

    float* ct  = (float*)d_ws;                       // 49152 f32
    float* st  = ct + 49152;                         // 49152 f32
    short* xb  = (short*)(st + 49152);               // 16384*384
    short* wt  = xb  + (size_t)16384 * 384;          // 576*384
    short* wot = wt  + (size_t)576 * 384;            // 384*384
    short* qb  = wot + (size_t)384 * 384;            // 8*8*2048*64 (d-padded)
    short* kb  = qb  + (size_t)B_ * HQ_  * T_ * 64;  // 8*2*2048*64 (d-padded)
    short* vtb = kb  + (size_t)B_ * HKV_ * T_ * 64;  // 8*2*48*2048 (transposed)
    short* aob = vtb + (size_t)B_ * HKV_ * D_ * T_;  // 16384*384
    // total ~50.4 MB

    hipLaunchKernelGGL(prep_kernel, dim3(7776), dim3(256), 0, stream,
                       x, wq, wk, wv, wo, xb, wt, wot, ct, st);
    // zero qb+kb (adjacent) so d-pad cols 48..63 are 0 for the MFMA K-dim
    hipMemsetAsync(qb, 0, ((size_t)B_ * HQ_ * T_ * 64 + (size_t)B_ * HKV_ * T_ * 64) * sizeof(short), stream);
    hipLaunchKernelGGL(qkv_gemm_kernel, dim3(9, 128), dim3(256), 0, stream,
                       xb, wt, ct, st, qb, kb, vtb);
    hipLaunchKernelGGL(attn_kernel, dim3(16, 8, 8), dim3(256), 0, stream,
                       qb, kb, vtb, aob);
    hipLaunchKernelGGL(out_gemm_kernel, dim3(6, 128), dim3(256), 0, stream,
                       aob, wot, bo, out);
}

// Round 10
// 206.277 us; speedup vs baseline: 1.1829x; 1.1829x over previous
//
#include <hip/hip_runtime.h>
#include <math.h>

#define B_   8
#define T_   2048
#define NE_  384
#define HQ_  8
#define HKV_ 2
#define D_   48
#define DH_  24   // D/2

typedef __attribute__((ext_vector_type(8))) short bf16x8;
typedef __attribute__((ext_vector_type(4))) short bf16x4;
typedef __attribute__((ext_vector_type(4))) float f32x4;

static __device__ __forceinline__ short f2bf(float f) {
    union { float f; unsigned u; } v; v.f = f;
    unsigned r = (v.u + 0x7fffu + ((v.u >> 16) & 1u)) >> 16;
    return (short)r;
}

// native 2^x (scores are pre-scaled by log2(e) in the QKV epilogue)
static __device__ __forceinline__ float exp2_fast(float x) {
    float r;
    asm("v_exp_f32 %0, %1" : "=v"(r) : "v"(x));
    return r;
}
// packed f32x2 -> bf16x2 RNE conversion, one instruction
static __device__ __forceinline__ unsigned cvt_pk_bf16(float lo, float hi) {
    unsigned r;
    asm("v_cvt_pk_bf16_f32 %0, %1, %2" : "=v"(r) : "v"(lo), "v"(hi));
    return r;
}
static __device__ __forceinline__ float max3f(float a, float b, float c) {
    float r;
    asm("v_max3_f32 %0, %1, %2, %3" : "=v"(r) : "v"(a), "v"(b), "v"(c));
    return r;
}
// async global->LDS DMA, 16B per lane (dest = wave-uniform base + lane*16)
static __device__ __forceinline__ void gld16(const void* g, void* l) {
    __builtin_amdgcn_global_load_lds(
        (const __attribute__((address_space(1))) unsigned int*)g,
        (__attribute__((address_space(3))) unsigned int*)l,
        16, 0, 0);
}

// ---------------- kernel 0: prep (convert + transpose + rope table) --------
__global__ __launch_bounds__(256) void prep_kernel(
    const float* __restrict__ x, const float* __restrict__ wq,
    const float* __restrict__ wk, const float* __restrict__ wv,
    const float* __restrict__ wo,
    short* __restrict__ xb, short* __restrict__ wt, short* __restrict__ wot,
    float* __restrict__ ct, float* __restrict__ st)
{
    const int bid = blockIdx.x, tid = threadIdx.x;
    if (bid < 6144) {
        int i = bid * 256 + tid;                 // float4 index, 1572864 total
        float4 v = ((const float4*)x)[i];
        bf16x4 o = { f2bf(v.x), f2bf(v.y), f2bf(v.z), f2bf(v.w) };
        *(bf16x4*)&xb[(size_t)i * 4] = o;
    } else if (bid < 7008) {
        int e = (bid - 6144) * 256 + tid;        // < 221184
        int n = e / 384, k = e - n * 384;
        float s = (n < 384) ? wq[(size_t)k * 384 + n]
                : (n < 480) ? wk[(size_t)k * 96 + (n - 384)]
                            : wv[(size_t)k * 96 + (n - 480)];
        wt[e] = f2bf(s);
    } else if (bid < 7584) {
        int e = (bid - 7008) * 256 + tid;        // < 147456
        int n = e / 384, k = e - n * 384;
        wot[e] = f2bf(wo[(size_t)k * 384 + n]);
    } else {
        int i = (bid - 7584) * 256 + tid;        // < 49152
        int t = i / DH_, j = i - t * DH_;
        double inv = pow(10000.0, -(double)(2 * j) / (double)D_);
        double ang = (double)t * inv;
        ct[i] = (float)cos(ang);
        st[i] = (float)sin(ang);
    }
}

// ---------------- kernel 1: QKV MFMA GEMM + fused RoPE ----------
// BK=64 double-buffered LDS via global_load_lds; pre-swizzled global source,
// matching XOR-swizzled ds_read_b128. One __syncthreads per K-tile.
__global__ __launch_bounds__(256) void qkv_gemm_kernel(
    const short* __restrict__ xb, const short* __restrict__ wt,
    const float* __restrict__ ct, const float* __restrict__ st,
    short* __restrict__ qb, short* __restrict__ kb, short* __restrict__ vtb)
{
    __shared__ __align__(16) char ldsb[49152];   // 2 x (A 16KB + B 8KB)
    const int tid = threadIdx.x;
    const int n0 = blockIdx.x * 64;     // 9 tiles
    const int m0 = blockIdx.y * 128;    // 128 tiles
    const int lane = tid & 63, w = tid >> 6;
    const int c = lane & 15, u = lane >> 4;
    const int mo = (w & 1) * 64, no = (w >> 1) * 32;
    const int lrow = lane >> 3;                          // 0..7 within 1KB chunk
    const int lcol = (((lane & 7) ^ lrow) << 4);         // swizzled src byte in 128B row
    f32x4 acc[4][2] = {};

    auto stage = [&](int bsel, int t) {
        char* dst = ldsb + bsel * 24576;
        const char* Ag = (const char*)xb + (size_t)(m0 + w * 32 + lrow) * 768 + t * 128 + lcol;
#pragma unroll
        for (int p = 0; p < 4; ++p)
            gld16(Ag + p * 8 * 768, dst + w * 4096 + p * 1024);
        const char* Bg = (const char*)wt + (size_t)(n0 + w * 16 + lrow) * 768 + t * 128 + lcol;
#pragma unroll
        for (int p = 0; p < 2; ++p)
            gld16(Bg + p * 8 * 768, dst + 16384 + w * 2048 + p * 1024);
    };

    stage(0, 0);
    __syncthreads();
    int cur = 0;
#pragma unroll 1
    for (int t = 0; t < 6; ++t) {
        if (t < 5) stage(cur ^ 1, t + 1);
        const char* Ab = ldsb + cur * 24576;
        const char* Bb = Ab + 16384;
#pragma unroll
        for (int kk = 0; kk < 2; ++kk) {
            const int off = (kk * 64 + u * 16) ^ ((c & 7) << 4);
            bf16x8 af[4], bfr[2];
#pragma unroll
            for (int i = 0; i < 4; ++i)
                af[i] = *(const bf16x8*)(Ab + (mo + 16 * i + c) * 128 + off);
#pragma unroll
            for (int j = 0; j < 2; ++j)
                bfr[j] = *(const bf16x8*)(Bb + (no + 16 * j + c) * 128 + off);
#pragma unroll
            for (int i = 0; i < 4; ++i)
#pragma unroll
                for (int j = 0; j < 2; ++j)
                    acc[i][j] = __builtin_amdgcn_mfma_f32_16x16x32_bf16(af[i], bfr[j], acc[i][j], 0, 0, 0);
        }
        __syncthreads();
        cur ^= 1;
    }

    // 1/sqrt(48) * log2(e): scores land in log2 domain so attn can use raw v_exp_f32
    const float qscale = 0.14433756729740643f * 1.4426950408889634f;
#pragma unroll
    for (int i = 0; i < 4; ++i) {
#pragma unroll
        for (int j = 0; j < 2; ++j) {
            int n = n0 + no + 16 * j + c;        // region uniform per 16-wide subtile
            int mb = m0 + mo + 16 * i + 4 * u;
            int b = mb >> 11;
            int t0 = mb & 2047;
            if (n < 480) {                       // q or k: RoPE, 64-padded store
                int nn = (n < 384) ? n : n - 384;
                int h = nn / 48, d = nn - h * 48;
                int fi = d >> 1;
                float sgn = (d & 1) ? 1.0f : -1.0f;
                float scl = (n < 384) ? qscale : 1.0f;
                short* dst = (n < 384) ? qb : kb;
                size_t base = (n < 384)
                    ? ((size_t)(b * HQ_ + h) * T_ + t0) * 64 + d
                    : ((size_t)(b * HKV_ + h) * T_ + t0) * 64 + d;
#pragma unroll
                for (int r = 0; r < 4; ++r) {
                    float val = acc[i][j][r];
                    float part = __shfl_xor(val, 1);
                    float cs = ct[(t0 + r) * DH_ + fi], sn = st[(t0 + r) * DH_ + fi];
                    dst[base + (size_t)r * 64] = f2bf((val * cs + sgn * part * sn) * scl);
                }
            } else {                             // v: no rope, transposed store
                int nn = n - 480;
                int h = nn / 48, d = nn - h * 48;
                ushort4 pk;
                pk.x = (unsigned short)f2bf(acc[i][j][0]);
                pk.y = (unsigned short)f2bf(acc[i][j][1]);
                pk.z = (unsigned short)f2bf(acc[i][j][2]);
                pk.w = (unsigned short)f2bf(acc[i][j][3]);
                *(ushort4*)&vtb[((size_t)(b * HKV_ + h) * D_ + d) * T_ + t0] = pk;
            }
        }
    }
}

// ---------------- kernel 2: LDS-staged fused-qt MFMA flash attention -------
// R5 structure (2 heads/block, bounds(256,2), 2 blocks/CU — the verified
// plateau) with the two qt passes MERGED into one jt sweep: stage each K/V
// tile ONCE and compute both Q-tiles (qt0=31-x, qt1=x) against it while
// resident. Barrier/stage rounds per block: 33 -> 32-x (avg 24.5, -26%);
// per-barrier MFMA density up ~35%; MFMA work stays balanced (33 tiles/blk).
__global__ __launch_bounds__(256, 2) void attn_kernel(
    const short* __restrict__ qb, const short* __restrict__ kb,
    const short* __restrict__ vtb, short* __restrict__ aob)
{
    __shared__ __align__(16) short lds_s[14336];   // 2 x (8KB K + 6KB V)
    const int tid = threadIdx.x;
    const int x  = blockIdx.x;          // 0..15
    const int hk = blockIdx.y >> 1;     // 0..1
    const int gp = blockIdx.y & 1;      // head pair within group
    const int b  = blockIdx.z;
    const int lane = tid & 63;
    const int w = tid >> 6;             // q-subtile: q rows 16w..16w+15
    const int c = lane & 15;
    const int u = lane >> 4;
    const int qt0 = 31 - x;             // 16..31
    const int qt1 = x;                  // 0..15  (qt1 < qt0 always)

    const char* kg = (const char*)kb  + (size_t)(b * HKV_ + hk) * T_ * 128;   // K rows 128B
    const char* vg = (const char*)vtb + (size_t)(b * HKV_ + hk) * D_ * T_ * 2; // V^T row stride 4096B

    // stage-side source swizzle (lane l fetches data belonging at phys l*16
    // after the (row&7)<<4 involution)
    const int swz  = (lane ^ ((lane >> 3) & 7)) << 4;   // within 1KB chunk (8 rows)
    const int vrow = lane >> 3;                          // 0..7
    const int voff = swz & 127;                          // within-row byte pos

    // read-side swizzle
    const int mk  = (c & 7) << 4;
    const int okl = (u * 16) ^ mk;            // K d 0..31 fragment
    const int okh = (64 | (u * 16)) ^ mk;     // K d 32..63 fragment

    auto stage = [&](int bsel, int jt) {
        char* dst = (char*)lds_s + bsel * 14336;
        const char* kt = kg + (size_t)jt * 8192;
        gld16(kt + (2 * w) * 1024 + swz,     dst + (2 * w) * 1024);
        gld16(kt + (2 * w + 1) * 1024 + swz, dst + (2 * w + 1) * 1024);
        if (w < 3) {                           // V: 6 chunks (48 rows x 128B)
            const char* vt = vg + (size_t)jt * 128;
            gld16(vt + (size_t)(16 * w + vrow) * 4096 + voff,
                  dst + 8192 + (2 * w) * 1024);
            gld16(vt + (size_t)(16 * w + 8 + vrow) * 4096 + voff,
                  dst + 8192 + (2 * w + 1) * 1024);
        }
    };

    // Q fragments for both qt-tiles, both heads
    bf16x8 qf0[2][2], qf1[2][2];        // [qs][g]
#pragma unroll
    for (int qs = 0; qs < 2; ++qs) {
        const int qt = qs ? qt1 : qt0;
#pragma unroll
        for (int g = 0; g < 2; ++g) {
            int h = hk * 4 + gp * 2 + g;
            const short* qp = qb + ((size_t)(b * HQ_ + h) * T_ + qt * 64 + 16 * w + c) * 64;
            qf0[qs][g] = *(const bf16x8*)(qp + 8 * u);          // d 0..31
            qf1[qs][g] = *(const bf16x8*)(qp + 32 + 8 * u);     // d 32..63 (pad=0)
        }
    }
    float m_s[2][2] = { { -1e30f, -1e30f }, { -1e30f, -1e30f } };
    float l_s[2][2] = {};
    f32x4 o[2][2][3] = {};

    int cur = 0;
    stage(0, 0);
    __syncthreads();

#pragma unroll 1
    for (int jt = 0; jt <= qt0; ++jt) {
        if (jt < qt0) stage(cur ^ 1, jt + 1);   // prefetch next tile

        const int fmax = (jt == qt0) ? (w + 1) : 4;   // frag-load bound
        const char* kbuf = (const char*)lds_s + cur * 14336;
        const char* vbuf = kbuf + 8192;

        bf16x8 klo[4], khi[4];
        bf16x4 vf[3][4];
#pragma unroll
        for (int mt = 0; mt < 4; ++mt) {
            if (mt < fmax) {
                klo[mt] = *(const bf16x8*)(kbuf + mt * 2048 + c * 128 + okl);
                khi[mt] = *(const bf16x8*)(kbuf + mt * 2048 + c * 128 + okh);
            }
        }
#pragma unroll
        for (int nt = 0; nt < 3; ++nt)
#pragma unroll
            for (int k2 = 0; k2 < 4; ++k2)
                if (k2 < fmax)
                    vf[nt][k2] = *(const bf16x4*)(vbuf + nt * 2048 + c * 128 +
                                                  (((k2 * 32) | (u * 8)) ^ mk));

#pragma unroll
        for (int qs = 0; qs < 2; ++qs) {
            const int qt = qs ? qt1 : qt0;
            if (qs == 1 && jt > qt1) continue;      // qt1 pass finished
            const bool diag = (jt == qt);
            const int mtmax = diag ? (w + 1) : 4;

#pragma unroll
            for (int g = 0; g < 2; ++g) {
                // S^T tiles: s[mt] = S^T[k=16mt+4u+r][q=16w+c]  (log2 domain)
                f32x4 s[4];
                __builtin_amdgcn_s_setprio(1);
#pragma unroll
                for (int mt = 0; mt < 4; ++mt) {
                    if (mt < mtmax) {
                        f32x4 a = {0.f, 0.f, 0.f, 0.f};
                        a = __builtin_amdgcn_mfma_f32_16x16x32_bf16(klo[mt], qf0[qs][g], a, 0, 0, 0);
                        a = __builtin_amdgcn_mfma_f32_16x16x32_bf16(khi[mt], qf1[qs][g], a, 0, 0, 0);
                        if (diag && mt == mtmax - 1) {      // diagonal 16x16 tile
#pragma unroll
                            for (int r = 0; r < 4; ++r)
                                a[r] = (4 * u + r > c) ? -1e30f : a[r];
                        }
                        s[mt] = a;
                    }
                }
                __builtin_amdgcn_s_setprio(0);

                float mloc = -1e30f;
#pragma unroll
                for (int mt = 0; mt < 4; ++mt)
                    if (mt < mtmax)
                        mloc = max3f(max3f(s[mt][0], s[mt][1], s[mt][2]), s[mt][3], mloc);
                mloc = fmaxf(mloc, __shfl_xor(mloc, 16));
                mloc = fmaxf(mloc, __shfl_xor(mloc, 32));   // per-q max (replicated over u)

                // T13 defer-max: rescale only when max grew by >8 (log2) => P <= 256
                if (__any(mloc > m_s[qs][g] + 8.0f)) {
                    float mnew = fmaxf(m_s[qs][g], mloc);
                    float alpha = exp2_fast(m_s[qs][g] - mnew);
                    m_s[qs][g] = mnew;
                    l_s[qs][g] *= alpha;
                    float a0 = __shfl(alpha, 4 * u + 0);
                    float a1 = __shfl(alpha, 4 * u + 1);
                    float a2 = __shfl(alpha, 4 * u + 2);
                    float a3 = __shfl(alpha, 4 * u + 3);
#pragma unroll
                    for (int nt = 0; nt < 3; ++nt) {
                        o[qs][g][nt][0] *= a0; o[qs][g][nt][1] *= a1;
                        o[qs][g][nt][2] *= a2; o[qs][g][nt][3] *= a3;
                    }
                }

                float psum = 0.0f;
                bf16x4 pf[4];
#pragma unroll
                for (int mt = 0; mt < 4; ++mt) {
                    if (mt < mtmax) {
                        float p0 = exp2_fast(s[mt][0] - m_s[qs][g]);
                        float p1 = exp2_fast(s[mt][1] - m_s[qs][g]);
                        float p2 = exp2_fast(s[mt][2] - m_s[qs][g]);
                        float p3 = exp2_fast(s[mt][3] - m_s[qs][g]);
                        psum += (p0 + p1) + (p2 + p3);
                        union { unsigned u2[2]; bf16x4 v; } pk;
                        pk.u2[0] = cvt_pk_bf16(p0, p1);
                        pk.u2[1] = cvt_pk_bf16(p2, p3);
                        pf[mt] = pk.v;
                    }
                }
                psum += __shfl_xor(psum, 16);
                psum += __shfl_xor(psum, 32);
                l_s[qs][g] += psum;

                __builtin_amdgcn_s_setprio(1);
#pragma unroll
                for (int k2 = 0; k2 < 4; ++k2) {
                    if (k2 < mtmax) {
#pragma unroll
                        for (int nt = 0; nt < 3; ++nt)
                            o[qs][g][nt] = __builtin_amdgcn_mfma_f32_16x16x16bf16_1k(
                                pf[k2], vf[nt][k2], o[qs][g][nt], 0, 0, 0);
                    }
                }
                __builtin_amdgcn_s_setprio(0);
            }
        }

        __syncthreads();        // vmcnt-drain (stage done) + buffer handoff
        cur ^= 1;
    }

    // epilogue: O rows 16w+4u+r, cols 16nt+c (per qt-tile, per head)
#pragma unroll
    for (int qs = 0; qs < 2; ++qs) {
        const int qt = qs ? qt1 : qt0;
#pragma unroll
        for (int g = 0; g < 2; ++g) {
            int h = hk * 4 + gp * 2 + g;
            float li = 1.0f / l_s[qs][g];
            float l0 = __shfl(li, 4 * u + 0);
            float l1 = __shfl(li, 4 * u + 1);
            float l2 = __shfl(li, 4 * u + 2);
            float l3 = __shfl(li, 4 * u + 3);
            float lr[4] = { l0, l1, l2, l3 };
#pragma unroll
            for (int nt = 0; nt < 3; ++nt)
#pragma unroll
                for (int r = 0; r < 4; ++r) {
                    int t = qt * 64 + 16 * w + 4 * u + r;
                    aob[((size_t)b * T_ + t) * NE_ + h * D_ + 16 * nt + c] =
                        f2bf(o[qs][g][nt][r] * lr[r]);
                }
        }
    }
}

// ---------------- kernel 3: out projection MFMA + bias ----------------
// Same BK=64 gld16 double-buffer structure as qkv_gemm.
__global__ __launch_bounds__(256) void out_gemm_kernel(
    const short* __restrict__ aob, const short* __restrict__ wot,
    const float* __restrict__ bias, float* __restrict__ out)
{
    __shared__ __align__(16) char ldsb[49152];
    const int tid = threadIdx.x;
    const int n0 = blockIdx.x * 64;     // 6 tiles
    const int m0 = blockIdx.y * 128;    // 128 tiles
    const int lane = tid & 63, w = tid >> 6;
    const int c = lane & 15, u = lane >> 4;
    const int mo = (w & 1) * 64, no = (w >> 1) * 32;
    const int lrow = lane >> 3;
    const int lcol = (((lane & 7) ^ lrow) << 4);
    f32x4 acc[4][2] = {};

    auto stage = [&](int bsel, int t) {
        char* dst = ldsb + bsel * 24576;
        const char* Ag = (const char*)aob + (size_t)(m0 + w * 32 + lrow) * 768 + t * 128 + lcol;
#pragma unroll
        for (int p = 0; p < 4; ++p)
            gld16(Ag + p * 8 * 768, dst + w * 4096 + p * 1024);
        const char* Bg = (const char*)wot + (size_t)(n0 + w * 16 + lrow) * 768 + t * 128 + lcol;
#pragma unroll
        for (int p = 0; p < 2; ++p)
            gld16(Bg + p * 8 * 768, dst + 16384 + w * 2048 + p * 1024);
    };

    stage(0, 0);
    __syncthreads();
    int cur = 0;
#pragma unroll 1
    for (int t = 0; t < 6; ++t) {
        if (t < 5) stage(cur ^ 1, t + 1);
        const char* Ab = ldsb + cur * 24576;
        const char* Bb = Ab + 16384;
#pragma unroll
        for (int kk = 0; kk < 2; ++kk) {
            const int off = (kk * 64 + u * 16) ^ ((c & 7) << 4);
            bf16x8 af[4], bfr[2];
#pragma unroll
            for (int i = 0; i < 4; ++i)
                af[i] = *(const bf16x8*)(Ab + (mo + 16 * i + c) * 128 + off);
#pragma unroll
            for (int j = 0; j < 2; ++j)
                bfr[j] = *(const bf16x8*)(Bb + (no + 16 * j + c) * 128 + off);
#pragma unroll
            for (int i = 0; i < 4; ++i)
#pragma unroll
                for (int j = 0; j < 2; ++j)
                    acc[i][j] = __builtin_amdgcn_mfma_f32_16x16x32_bf16(af[i], bfr[j], acc[i][j], 0, 0, 0);
        }
        __syncthreads();
        cur ^= 1;
    }

#pragma unroll
    for (int i = 0; i < 4; ++i) {
#pragma unroll
        for (int j = 0; j < 2; ++j) {
            int n = n0 + no + 16 * j + c;
            int mb = m0 + mo + 16 * i + 4 * u;
            float bv = bias[n];
#pragma unroll
            for (int r = 0; r < 4; ++r)
                out[(size_t)(mb + r) * 384 + n] = acc[i][j][r] + bv;
        }
    }
}

// ---------------- launcher ----------------
extern "C" void kernel_launch(void* const* d_in, const int* in_sizes, int n_in,
                              void* d_out, int out_size, void* d_ws, size_t ws_size,
                              hipStream_t stream) {
    const float* x  = (const float*)d_in[0];
    const float* wq = (const float*)d_in[1];
    const float* wk = (const float*)d_in[2];
    const float* wv = (const float*)d_in[3];
    const float* wo = (const float*)d_in[4];
    const float* bo = (const float*)d_in[5];
    float* out = (float*)d_out;

    float* ct  = (float*)d_ws;                       // 49152 f32
    float* st  = ct + 49152;                         // 49152 f32
    short* xb  = (short*)(st + 49152);               // 16384*384
    short* wt  = xb  + (size_t)16384 * 384;          // 576*384
    short* wot = wt  + (size_t)576 * 384;            // 384*384
    short* qb  = wot + (size_t)384 * 384;            // 8*8*2048*64 (d-padded)
    short* kb  = qb  + (size_t)B_ * HQ_  * T_ * 64;  // 8*2*2048*64 (d-padded)
    short* vtb = kb  + (size_t)B_ * HKV_ * T_ * 64;  // 8*2*48*2048 (transposed)
    short* aob = vtb + (size_t)B_ * HKV_ * D_ * T_;  // 16384*384
    // total ~50.4 MB

    hipLaunchKernelGGL(prep_kernel, dim3(7776), dim3(256), 0, stream,
                       x, wq, wk, wv, wo, xb, wt, wot, ct, st);
    // zero qb+kb (adjacent) so d-pad cols 48..63 are 0 for the MFMA K-dim
    hipMemsetAsync(qb, 0, ((size_t)B_ * HQ_ * T_ * 64 + (size_t)B_ * HKV_ * T_ * 64) * sizeof(short), stream);
    hipLaunchKernelGGL(qkv_gemm_kernel, dim3(9, 128), dim3(256), 0, stream,
                       xb, wt, ct, st, qb, kb, vtb);
    hipLaunchKernelGGL(attn_kernel, dim3(16, 4, 8), dim3(256), 0, stream,
                       qb, kb, vtb, aob);
    hipLaunchKernelGGL(out_gemm_kernel, dim3(6, 128), dim3(256), 0, stream,
                       aob, wot, bo, out);
}

// Round 11
// 199.465 us; speedup vs baseline: 1.2233x; 1.0342x over previous
//
#include <hip/hip_runtime.h>
#include <math.h>

#define B_   8
#define T_   2048
#define NE_  384
#define HQ_  8
#define HKV_ 2
#define D_   48
#define DH_  24   // D/2

typedef __attribute__((ext_vector_type(8))) short bf16x8;
typedef __attribute__((ext_vector_type(4))) short bf16x4;
typedef __attribute__((ext_vector_type(4))) float f32x4;

static __device__ __forceinline__ short f2bf(float f) {
    union { float f; unsigned u; } v; v.f = f;
    unsigned r = (v.u + 0x7fffu + ((v.u >> 16) & 1u)) >> 16;
    return (short)r;
}

// native 2^x (scores are pre-scaled by log2(e) in the QKV epilogue)
static __device__ __forceinline__ float exp2_fast(float x) {
    float r;
    asm("v_exp_f32 %0, %1" : "=v"(r) : "v"(x));
    return r;
}
// packed f32x2 -> bf16x2 RNE conversion, one instruction
static __device__ __forceinline__ unsigned cvt_pk_bf16(float lo, float hi) {
    unsigned r;
    asm("v_cvt_pk_bf16_f32 %0, %1, %2" : "=v"(r) : "v"(lo), "v"(hi));
    return r;
}
static __device__ __forceinline__ float max3f(float a, float b, float c) {
    float r;
    asm("v_max3_f32 %0, %1, %2, %3" : "=v"(r) : "v"(a), "v"(b), "v"(c));
    return r;
}
// async global->LDS DMA, 16B per lane (dest = wave-uniform base + lane*16)
static __device__ __forceinline__ void gld16(const void* g, void* l) {
    __builtin_amdgcn_global_load_lds(
        (const __attribute__((address_space(1))) unsigned int*)g,
        (__attribute__((address_space(3))) unsigned int*)l,
        16, 0, 0);
}

// ---------------- kernel 0: prep (convert + transpose + rope + pad-zero) ---
// Pad-zero section replaces the 21MB hipMemsetAsync (only the 5.2MB d-pad
// cols 48..63 of qb/kb actually need zeroing) — one fewer dispatch, -16MB
// writes. Rope table in f32 (reference computes angles in f32 too).
__global__ __launch_bounds__(256) void prep_kernel(
    const float* __restrict__ x, const float* __restrict__ wq,
    const float* __restrict__ wk, const float* __restrict__ wv,
    const float* __restrict__ wo,
    short* __restrict__ xb, short* __restrict__ wt, short* __restrict__ wot,
    float* __restrict__ ct, float* __restrict__ st,
    short* __restrict__ qb)
{
    const int bid = blockIdx.x, tid = threadIdx.x;
    if (bid < 6144) {
        int i = bid * 256 + tid;                 // float4 index, 1572864 total
        float4 v = ((const float4*)x)[i];
        bf16x4 o = { f2bf(v.x), f2bf(v.y), f2bf(v.z), f2bf(v.w) };
        *(bf16x4*)&xb[(size_t)i * 4] = o;
    } else if (bid < 7008) {
        int e = (bid - 6144) * 256 + tid;        // < 221184
        int n = e / 384, k = e - n * 384;
        float s = (n < 384) ? wq[(size_t)k * 384 + n]
                : (n < 480) ? wk[(size_t)k * 96 + (n - 384)]
                            : wv[(size_t)k * 96 + (n - 480)];
        wt[e] = f2bf(s);
    } else if (bid < 7584) {
        int e = (bid - 7008) * 256 + tid;        // < 147456
        int n = e / 384, k = e - n * 384;
        wot[e] = f2bf(wo[(size_t)k * 384 + n]);
    } else if (bid < 7776) {
        int i = (bid - 7584) * 256 + tid;        // < 49152
        int t = i / DH_, j = i - t * DH_;
        float inv = powf(10000.0f, -(float)(2 * j) / (float)D_);
        float ang = (float)t * inv;
        float sv, cv;
        __sincosf(ang, &sv, &cv);
        ct[i] = cv;
        st[i] = sv;
    } else {
        // zero d-pad cols 48..63 of qb (131072 rows) + kb (32768 rows, adjacent)
        int i = (bid - 7776) * 256 + tid;        // < 327680
        int row = i >> 1, half = i & 1;
        bf16x8 z = {};
        *(bf16x8*)&qb[(size_t)row * 64 + 48 + half * 8] = z;
    }
}

// ---------------- kernel 1: QKV MFMA GEMM + fused RoPE ----------
// BK=64 double-buffered LDS via global_load_lds; pre-swizzled global source,
// matching XOR-swizzled ds_read_b128. One __syncthreads per K-tile.
__global__ __launch_bounds__(256) void qkv_gemm_kernel(
    const short* __restrict__ xb, const short* __restrict__ wt,
    const float* __restrict__ ct, const float* __restrict__ st,
    short* __restrict__ qb, short* __restrict__ kb, short* __restrict__ vtb)
{
    __shared__ __align__(16) char ldsb[49152];   // 2 x (A 16KB + B 8KB)
    const int tid = threadIdx.x;
    const int n0 = blockIdx.x * 64;     // 9 tiles
    const int m0 = blockIdx.y * 128;    // 128 tiles
    const int lane = tid & 63, w = tid >> 6;
    const int c = lane & 15, u = lane >> 4;
    const int mo = (w & 1) * 64, no = (w >> 1) * 32;
    const int lrow = lane >> 3;                          // 0..7 within 1KB chunk
    const int lcol = (((lane & 7) ^ lrow) << 4);         // swizzled src byte in 128B row
    f32x4 acc[4][2] = {};

    auto stage = [&](int bsel, int t) {
        char* dst = ldsb + bsel * 24576;
        const char* Ag = (const char*)xb + (size_t)(m0 + w * 32 + lrow) * 768 + t * 128 + lcol;
#pragma unroll
        for (int p = 0; p < 4; ++p)
            gld16(Ag + p * 8 * 768, dst + w * 4096 + p * 1024);
        const char* Bg = (const char*)wt + (size_t)(n0 + w * 16 + lrow) * 768 + t * 128 + lcol;
#pragma unroll
        for (int p = 0; p < 2; ++p)
            gld16(Bg + p * 8 * 768, dst + 16384 + w * 2048 + p * 1024);
    };

    stage(0, 0);
    __syncthreads();
    int cur = 0;
#pragma unroll 1
    for (int t = 0; t < 6; ++t) {
        if (t < 5) stage(cur ^ 1, t + 1);
        const char* Ab = ldsb + cur * 24576;
        const char* Bb = Ab + 16384;
#pragma unroll
        for (int kk = 0; kk < 2; ++kk) {
            const int off = (kk * 64 + u * 16) ^ ((c & 7) << 4);
            bf16x8 af[4], bfr[2];
#pragma unroll
            for (int i = 0; i < 4; ++i)
                af[i] = *(const bf16x8*)(Ab + (mo + 16 * i + c) * 128 + off);
#pragma unroll
            for (int j = 0; j < 2; ++j)
                bfr[j] = *(const bf16x8*)(Bb + (no + 16 * j + c) * 128 + off);
#pragma unroll
            for (int i = 0; i < 4; ++i)
#pragma unroll
                for (int j = 0; j < 2; ++j)
                    acc[i][j] = __builtin_amdgcn_mfma_f32_16x16x32_bf16(af[i], bfr[j], acc[i][j], 0, 0, 0);
        }
        __syncthreads();
        cur ^= 1;
    }

    // 1/sqrt(48) * log2(e): scores land in log2 domain so attn can use raw v_exp_f32
    const float qscale = 0.14433756729740643f * 1.4426950408889634f;
#pragma unroll
    for (int i = 0; i < 4; ++i) {
#pragma unroll
        for (int j = 0; j < 2; ++j) {
            int n = n0 + no + 16 * j + c;        // region uniform per 16-wide subtile
            int mb = m0 + mo + 16 * i + 4 * u;
            int b = mb >> 11;
            int t0 = mb & 2047;
            if (n < 480) {                       // q or k: RoPE, 64-padded store
                int nn = (n < 384) ? n : n - 384;
                int h = nn / 48, d = nn - h * 48;
                int fi = d >> 1;
                float sgn = (d & 1) ? 1.0f : -1.0f;
                float scl = (n < 384) ? qscale : 1.0f;
                short* dst = (n < 384) ? qb : kb;
                size_t base = (n < 384)
                    ? ((size_t)(b * HQ_ + h) * T_ + t0) * 64 + d
                    : ((size_t)(b * HKV_ + h) * T_ + t0) * 64 + d;
#pragma unroll
                for (int r = 0; r < 4; ++r) {
                    float val = acc[i][j][r];
                    float part = __shfl_xor(val, 1);
                    float cs = ct[(t0 + r) * DH_ + fi], sn = st[(t0 + r) * DH_ + fi];
                    dst[base + (size_t)r * 64] = f2bf((val * cs + sgn * part * sn) * scl);
                }
            } else {                             // v: no rope, transposed store
                int nn = n - 480;
                int h = nn / 48, d = nn - h * 48;
                ushort4 pk;
                pk.x = (unsigned short)f2bf(acc[i][j][0]);
                pk.y = (unsigned short)f2bf(acc[i][j][1]);
                pk.z = (unsigned short)f2bf(acc[i][j][2]);
                pk.w = (unsigned short)f2bf(acc[i][j][3]);
                *(ushort4*)&vtb[((size_t)(b * HKV_ + h) * D_ + d) * T_ + t0] = pk;
            }
        }
    }
}

// ---------------- kernel 2: LDS-staged fused-qt MFMA flash attention -------
// R10 structure (fused qt-pair, 2 heads/block, 2 blocks/CU plateau) with the
// l-reduction DEFERRED out of the jt loop: l_s keeps per-lane partials (the
// per-unit 2x __shfl_xor was pure DS latency on the critical path; alpha is
// q-uniform across u so rescale commutes with the deferred sum), reduced once
// in the epilogue. Math identical.
__global__ __launch_bounds__(256, 2) void attn_kernel(
    const short* __restrict__ qb, const short* __restrict__ kb,
    const short* __restrict__ vtb, short* __restrict__ aob)
{
    __shared__ __align__(16) short lds_s[14336];   // 2 x (8KB K + 6KB V)
    const int tid = threadIdx.x;
    const int x  = blockIdx.x;          // 0..15
    const int hk = blockIdx.y >> 1;     // 0..1
    const int gp = blockIdx.y & 1;      // head pair within group
    const int b  = blockIdx.z;
    const int lane = tid & 63;
    const int w = tid >> 6;             // q-subtile: q rows 16w..16w+15
    const int c = lane & 15;
    const int u = lane >> 4;
    const int qt0 = 31 - x;             // 16..31
    const int qt1 = x;                  // 0..15  (qt1 < qt0 always)

    const char* kg = (const char*)kb  + (size_t)(b * HKV_ + hk) * T_ * 128;   // K rows 128B
    const char* vg = (const char*)vtb + (size_t)(b * HKV_ + hk) * D_ * T_ * 2; // V^T row stride 4096B

    // stage-side source swizzle (lane l fetches data belonging at phys l*16
    // after the (row&7)<<4 involution)
    const int swz  = (lane ^ ((lane >> 3) & 7)) << 4;   // within 1KB chunk (8 rows)
    const int vrow = lane >> 3;                          // 0..7
    const int voff = swz & 127;                          // within-row byte pos

    // read-side swizzle
    const int mk  = (c & 7) << 4;
    const int okl = (u * 16) ^ mk;            // K d 0..31 fragment
    const int okh = (64 | (u * 16)) ^ mk;     // K d 32..63 fragment

    auto stage = [&](int bsel, int jt) {
        char* dst = (char*)lds_s + bsel * 14336;
        const char* kt = kg + (size_t)jt * 8192;
        gld16(kt + (2 * w) * 1024 + swz,     dst + (2 * w) * 1024);
        gld16(kt + (2 * w + 1) * 1024 + swz, dst + (2 * w + 1) * 1024);
        if (w < 3) {                           // V: 6 chunks (48 rows x 128B)
            const char* vt = vg + (size_t)jt * 128;
            gld16(vt + (size_t)(16 * w + vrow) * 4096 + voff,
                  dst + 8192 + (2 * w) * 1024);
            gld16(vt + (size_t)(16 * w + 8 + vrow) * 4096 + voff,
                  dst + 8192 + (2 * w + 1) * 1024);
        }
    };

    // Q fragments for both qt-tiles, both heads
    bf16x8 qf0[2][2], qf1[2][2];        // [qs][g]
#pragma unroll
    for (int qs = 0; qs < 2; ++qs) {
        const int qt = qs ? qt1 : qt0;
#pragma unroll
        for (int g = 0; g < 2; ++g) {
            int h = hk * 4 + gp * 2 + g;
            const short* qp = qb + ((size_t)(b * HQ_ + h) * T_ + qt * 64 + 16 * w + c) * 64;
            qf0[qs][g] = *(const bf16x8*)(qp + 8 * u);          // d 0..31
            qf1[qs][g] = *(const bf16x8*)(qp + 32 + 8 * u);     // d 32..63 (pad=0)
        }
    }
    float m_s[2][2] = { { -1e30f, -1e30f }, { -1e30f, -1e30f } };
    float l_s[2][2] = {};               // per-lane partial sums (reduced in epilogue)
    f32x4 o[2][2][3] = {};

    int cur = 0;
    stage(0, 0);
    __syncthreads();

#pragma unroll 1
    for (int jt = 0; jt <= qt0; ++jt) {
        if (jt < qt0) stage(cur ^ 1, jt + 1);   // prefetch next tile

        const int fmax = (jt == qt0) ? (w + 1) : 4;   // frag-load bound
        const char* kbuf = (const char*)lds_s + cur * 14336;
        const char* vbuf = kbuf + 8192;

        bf16x8 klo[4], khi[4];
        bf16x4 vf[3][4];
#pragma unroll
        for (int mt = 0; mt < 4; ++mt) {
            if (mt < fmax) {
                klo[mt] = *(const bf16x8*)(kbuf + mt * 2048 + c * 128 + okl);
                khi[mt] = *(const bf16x8*)(kbuf + mt * 2048 + c * 128 + okh);
            }
        }
#pragma unroll
        for (int nt = 0; nt < 3; ++nt)
#pragma unroll
            for (int k2 = 0; k2 < 4; ++k2)
                if (k2 < fmax)
                    vf[nt][k2] = *(const bf16x4*)(vbuf + nt * 2048 + c * 128 +
                                                  (((k2 * 32) | (u * 8)) ^ mk));

#pragma unroll
        for (int qs = 0; qs < 2; ++qs) {
            const int qt = qs ? qt1 : qt0;
            if (qs == 1 && jt > qt1) continue;      // qt1 pass finished
            const bool diag = (jt == qt);
            const int mtmax = diag ? (w + 1) : 4;

#pragma unroll
            for (int g = 0; g < 2; ++g) {
                // S^T tiles: s[mt] = S^T[k=16mt+4u+r][q=16w+c]  (log2 domain)
                f32x4 s[4];
                __builtin_amdgcn_s_setprio(1);
#pragma unroll
                for (int mt = 0; mt < 4; ++mt) {
                    if (mt < mtmax) {
                        f32x4 a = {0.f, 0.f, 0.f, 0.f};
                        a = __builtin_amdgcn_mfma_f32_16x16x32_bf16(klo[mt], qf0[qs][g], a, 0, 0, 0);
                        a = __builtin_amdgcn_mfma_f32_16x16x32_bf16(khi[mt], qf1[qs][g], a, 0, 0, 0);
                        if (diag && mt == mtmax - 1) {      // diagonal 16x16 tile
#pragma unroll
                            for (int r = 0; r < 4; ++r)
                                a[r] = (4 * u + r > c) ? -1e30f : a[r];
                        }
                        s[mt] = a;
                    }
                }
                __builtin_amdgcn_s_setprio(0);

                float mloc = -1e30f;
#pragma unroll
                for (int mt = 0; mt < 4; ++mt)
                    if (mt < mtmax)
                        mloc = max3f(max3f(s[mt][0], s[mt][1], s[mt][2]), s[mt][3], mloc);
                mloc = fmaxf(mloc, __shfl_xor(mloc, 16));
                mloc = fmaxf(mloc, __shfl_xor(mloc, 32));   // per-q max (replicated over u)

                // T13 defer-max: rescale only when max grew by >8 (log2) => P <= 256
                if (__any(mloc > m_s[qs][g] + 8.0f)) {
                    float mnew = fmaxf(m_s[qs][g], mloc);
                    float alpha = exp2_fast(m_s[qs][g] - mnew);   // q-uniform across u
                    m_s[qs][g] = mnew;
                    l_s[qs][g] *= alpha;                          // per-lane partial scales
                    float a0 = __shfl(alpha, 4 * u + 0);
                    float a1 = __shfl(alpha, 4 * u + 1);
                    float a2 = __shfl(alpha, 4 * u + 2);
                    float a3 = __shfl(alpha, 4 * u + 3);
#pragma unroll
                    for (int nt = 0; nt < 3; ++nt) {
                        o[qs][g][nt][0] *= a0; o[qs][g][nt][1] *= a1;
                        o[qs][g][nt][2] *= a2; o[qs][g][nt][3] *= a3;
                    }
                }

                bf16x4 pf[4];
#pragma unroll
                for (int mt = 0; mt < 4; ++mt) {
                    if (mt < mtmax) {
                        float p0 = exp2_fast(s[mt][0] - m_s[qs][g]);
                        float p1 = exp2_fast(s[mt][1] - m_s[qs][g]);
                        float p2 = exp2_fast(s[mt][2] - m_s[qs][g]);
                        float p3 = exp2_fast(s[mt][3] - m_s[qs][g]);
                        l_s[qs][g] += (p0 + p1) + (p2 + p3);      // per-lane, no shfl
                        union { unsigned u2[2]; bf16x4 v; } pk;
                        pk.u2[0] = cvt_pk_bf16(p0, p1);
                        pk.u2[1] = cvt_pk_bf16(p2, p3);
                        pf[mt] = pk.v;
                    }
                }

                __builtin_amdgcn_s_setprio(1);
#pragma unroll
                for (int k2 = 0; k2 < 4; ++k2) {
                    if (k2 < mtmax) {
#pragma unroll
                        for (int nt = 0; nt < 3; ++nt)
                            o[qs][g][nt] = __builtin_amdgcn_mfma_f32_16x16x16bf16_1k(
                                pf[k2], vf[nt][k2], o[qs][g][nt], 0, 0, 0);
                    }
                }
                __builtin_amdgcn_s_setprio(0);
            }
        }

        __syncthreads();        // vmcnt-drain (stage done) + buffer handoff
        cur ^= 1;
    }

    // epilogue: deferred l-reduction (once, was per-jt), then O writeback
#pragma unroll
    for (int qs = 0; qs < 2; ++qs) {
        const int qt = qs ? qt1 : qt0;
#pragma unroll
        for (int g = 0; g < 2; ++g) {
            int h = hk * 4 + gp * 2 + g;
            float lt = l_s[qs][g];
            lt += __shfl_xor(lt, 16);
            lt += __shfl_xor(lt, 32);           // full sum for q=c, replicated
            float li = 1.0f / lt;
            float l0 = __shfl(li, 4 * u + 0);
            float l1 = __shfl(li, 4 * u + 1);
            float l2 = __shfl(li, 4 * u + 2);
            float l3 = __shfl(li, 4 * u + 3);
            float lr[4] = { l0, l1, l2, l3 };
#pragma unroll
            for (int nt = 0; nt < 3; ++nt)
#pragma unroll
                for (int r = 0; r < 4; ++r) {
                    int t = qt * 64 + 16 * w + 4 * u + r;
                    aob[((size_t)b * T_ + t) * NE_ + h * D_ + 16 * nt + c] =
                        f2bf(o[qs][g][nt][r] * lr[r]);
                }
        }
    }
}

// ---------------- kernel 3: out projection MFMA + bias ----------------
// Same BK=64 gld16 double-buffer structure as qkv_gemm.
__global__ __launch_bounds__(256) void out_gemm_kernel(
    const short* __restrict__ aob, const short* __restrict__ wot,
    const float* __restrict__ bias, float* __restrict__ out)
{
    __shared__ __align__(16) char ldsb[49152];
    const int tid = threadIdx.x;
    const int n0 = blockIdx.x * 64;     // 6 tiles
    const int m0 = blockIdx.y * 128;    // 128 tiles
    const int lane = tid & 63, w = tid >> 6;
    const int c = lane & 15, u = lane >> 4;
    const int mo = (w & 1) * 64, no = (w >> 1) * 32;
    const int lrow = lane >> 3;
    const int lcol = (((lane & 7) ^ lrow) << 4);
    f32x4 acc[4][2] = {};

    auto stage = [&](int bsel, int t) {
        char* dst = ldsb + bsel * 24576;
        const char* Ag = (const char*)aob + (size_t)(m0 + w * 32 + lrow) * 768 + t * 128 + lcol;
#pragma unroll
        for (int p = 0; p < 4; ++p)
            gld16(Ag + p * 8 * 768, dst + w * 4096 + p * 1024);
        const char* Bg = (const char*)wot + (size_t)(n0 + w * 16 + lrow) * 768 + t * 128 + lcol;
#pragma unroll
        for (int p = 0; p < 2; ++p)
            gld16(Bg + p * 8 * 768, dst + 16384 + w * 2048 + p * 1024);
    };

    stage(0, 0);
    __syncthreads();
    int cur = 0;
#pragma unroll 1
    for (int t = 0; t < 6; ++t) {
        if (t < 5) stage(cur ^ 1, t + 1);
        const char* Ab = ldsb + cur * 24576;
        const char* Bb = Ab + 16384;
#pragma unroll
        for (int kk = 0; kk < 2; ++kk) {
            const int off = (kk * 64 + u * 16) ^ ((c & 7) << 4);
            bf16x8 af[4], bfr[2];
#pragma unroll
            for (int i = 0; i < 4; ++i)
                af[i] = *(const bf16x8*)(Ab + (mo + 16 * i + c) * 128 + off);
#pragma unroll
            for (int j = 0; j < 2; ++j)
                bfr[j] = *(const bf16x8*)(Bb + (no + 16 * j + c) * 128 + off);
#pragma unroll
            for (int i = 0; i < 4; ++i)
#pragma unroll
                for (int j = 0; j < 2; ++j)
                    acc[i][j] = __builtin_amdgcn_mfma_f32_16x16x32_bf16(af[i], bfr[j], acc[i][j], 0, 0, 0);
        }
        __syncthreads();
        cur ^= 1;
    }

#pragma unroll
    for (int i = 0; i < 4; ++i) {
#pragma unroll
        for (int j = 0; j < 2; ++j) {
            int n = n0 + no + 16 * j + c;
            int mb = m0 + mo + 16 * i + 4 * u;
            float bv = bias[n];
#pragma unroll
            for (int r = 0; r < 4; ++r)
                out[(size_t)(mb + r) * 384 + n] = acc[i][j][r] + bv;
        }
    }
}

// ---------------- launcher ----------------
extern "C" void kernel_launch(void* const* d_in, const int* in_sizes, int n_in,
                              void* d_out, int out_size, void* d_ws, size_t ws_size,
                              hipStream_t stream) {
    const float* x  = (const float*)d_in[0];
    const float* wq = (const float*)d_in[1];
    const float* wk = (const float*)d_in[2];
    const float* wv = (const float*)d_in[3];
    const float* wo = (const float*)d_in[4];
    const float* bo = (const float*)d_in[5];
    float* out = (float*)d_out;

    float* ct  = (float*)d_ws;                       // 49152 f32
    float* st  = ct + 49152;                         // 49152 f32
    short* xb  = (short*)(st + 49152);               // 16384*384
    short* wt  = xb  + (size_t)16384 * 384;          // 576*384
    short* wot = wt  + (size_t)576 * 384;            // 384*384
    short* qb  = wot + (size_t)384 * 384;            // 8*8*2048*64 (d-padded)
    short* kb  = qb  + (size_t)B_ * HQ_  * T_ * 64;  // 8*2*2048*64 (d-padded)
    short* vtb = kb  + (size_t)B_ * HKV_ * T_ * 64;  // 8*2*48*2048 (transposed)
    short* aob = vtb + (size_t)B_ * HKV_ * D_ * T_;  // 16384*384
    // total ~50.4 MB

    // prep now also zeroes the qb/kb d-pad (cols 48..63) — no memset needed
    hipLaunchKernelGGL(prep_kernel, dim3(9056), dim3(256), 0, stream,
                       x, wq, wk, wv, wo, xb, wt, wot, ct, st, qb);
    hipLaunchKernelGGL(qkv_gemm_kernel, dim3(9, 128), dim3(256), 0, stream,
                       xb, wt, ct, st, qb, kb, vtb);
    hipLaunchKernelGGL(attn_kernel, dim3(16, 4, 8), dim3(256), 0, stream,
                       qb, kb, vtb, aob);
    hipLaunchKernelGGL(out_gemm_kernel, dim3(6, 128), dim3(256), 0, stream,
                       aob, wot, bo, out);
}

// Round 13
// 185.380 us; speedup vs baseline: 1.3162x; 1.0760x over previous
//
#include <hip/hip_runtime.h>
#include <math.h>

#define B_   8
#define T_   2048
#define NE_  384
#define HQ_  8
#define HKV_ 2
#define D_   48
#define DH_  24   // D/2

typedef __attribute__((ext_vector_type(8))) short bf16x8;
typedef __attribute__((ext_vector_type(4))) short bf16x4;
typedef __attribute__((ext_vector_type(4))) float f32x4;

static __device__ __forceinline__ short f2bf(float f) {
    union { float f; unsigned u; } v; v.f = f;
    unsigned r = (v.u + 0x7fffu + ((v.u >> 16) & 1u)) >> 16;
    return (short)r;
}

// native 2^x (scores are pre-scaled by log2(e) in the QKV epilogue)
static __device__ __forceinline__ float exp2_fast(float x) {
    float r;
    asm("v_exp_f32 %0, %1" : "=v"(r) : "v"(x));
    return r;
}
// packed f32x2 -> bf16x2 RNE conversion, one instruction
static __device__ __forceinline__ unsigned cvt_pk_bf16(float lo, float hi) {
    unsigned r;
    asm("v_cvt_pk_bf16_f32 %0, %1, %2" : "=v"(r) : "v"(lo), "v"(hi));
    return r;
}
static __device__ __forceinline__ float max3f(float a, float b, float c) {
    float r;
    asm("v_max3_f32 %0, %1, %2, %3" : "=v"(r) : "v"(a), "v"(b), "v"(c));
    return r;
}
// async global->LDS DMA, 16B per lane (dest = wave-uniform base + lane*16)
static __device__ __forceinline__ void gld16(const void* g, void* l) {
    __builtin_amdgcn_global_load_lds(
        (const __attribute__((address_space(1))) unsigned int*)g,
        (__attribute__((address_space(3))) unsigned int*)l,
        16, 0, 0);
}

// ---------------- kernel 0: prep (convert + transpose + rope + pad-zero) ---
__global__ __launch_bounds__(256) void prep_kernel(
    const float* __restrict__ x, const float* __restrict__ wq,
    const float* __restrict__ wk, const float* __restrict__ wv,
    const float* __restrict__ wo,
    short* __restrict__ xb, short* __restrict__ wt, short* __restrict__ wot,
    float* __restrict__ ct, float* __restrict__ st,
    short* __restrict__ qb)
{
    const int bid = blockIdx.x, tid = threadIdx.x;
    if (bid < 6144) {
        int i = bid * 256 + tid;                 // float4 index, 1572864 total
        float4 v = ((const float4*)x)[i];
        bf16x4 o = { f2bf(v.x), f2bf(v.y), f2bf(v.z), f2bf(v.w) };
        *(bf16x4*)&xb[(size_t)i * 4] = o;
    } else if (bid < 7008) {
        int e = (bid - 6144) * 256 + tid;        // < 221184
        int n = e / 384, k = e - n * 384;
        float s = (n < 384) ? wq[(size_t)k * 384 + n]
                : (n < 480) ? wk[(size_t)k * 96 + (n - 384)]
                            : wv[(size_t)k * 96 + (n - 480)];
        wt[e] = f2bf(s);
    } else if (bid < 7584) {
        int e = (bid - 7008) * 256 + tid;        // < 147456
        int n = e / 384, k = e - n * 384;
        wot[e] = f2bf(wo[(size_t)k * 384 + n]);
    } else if (bid < 7776) {
        int i = (bid - 7584) * 256 + tid;        // < 49152
        int t = i / DH_, j = i - t * DH_;
        float inv = powf(10000.0f, -(float)(2 * j) / (float)D_);
        float ang = (float)t * inv;
        float sv, cv;
        __sincosf(ang, &sv, &cv);
        ct[i] = cv;
        st[i] = sv;
    } else {
        // zero d-pad cols 48..63 of qb (131072 rows) + kb (32768 rows, adjacent)
        int i = (bid - 7776) * 256 + tid;        // < 327680
        int row = i >> 1, half = i & 1;
        bf16x8 z = {};
        *(bf16x8*)&qb[(size_t)row * 64 + 48 + half * 8] = z;
    }
}

// ---------------- kernel 1: QKV MFMA GEMM + fused RoPE ----------
__global__ __launch_bounds__(256) void qkv_gemm_kernel(
    const short* __restrict__ xb, const short* __restrict__ wt,
    const float* __restrict__ ct, const float* __restrict__ st,
    short* __restrict__ qb, short* __restrict__ kb, short* __restrict__ vtb)
{
    __shared__ __align__(16) char ldsb[49152];   // 2 x (A 16KB + B 8KB)
    const int tid = threadIdx.x;
    const int n0 = blockIdx.x * 64;     // 9 tiles
    const int m0 = blockIdx.y * 128;    // 128 tiles
    const int lane = tid & 63, w = tid >> 6;
    const int c = lane & 15, u = lane >> 4;
    const int mo = (w & 1) * 64, no = (w >> 1) * 32;
    const int lrow = lane >> 3;                          // 0..7 within 1KB chunk
    const int lcol = (((lane & 7) ^ lrow) << 4);         // swizzled src byte in 128B row
    f32x4 acc[4][2] = {};

    auto stage = [&](int bsel, int t) {
        char* dst = ldsb + bsel * 24576;
        const char* Ag = (const char*)xb + (size_t)(m0 + w * 32 + lrow) * 768 + t * 128 + lcol;
#pragma unroll
        for (int p = 0; p < 4; ++p)
            gld16(Ag + p * 8 * 768, dst + w * 4096 + p * 1024);
        const char* Bg = (const char*)wt + (size_t)(n0 + w * 16 + lrow) * 768 + t * 128 + lcol;
#pragma unroll
        for (int p = 0; p < 2; ++p)
            gld16(Bg + p * 8 * 768, dst + 16384 + w * 2048 + p * 1024);
    };

    stage(0, 0);
    __syncthreads();
    int cur = 0;
#pragma unroll 1
    for (int t = 0; t < 6; ++t) {
        if (t < 5) stage(cur ^ 1, t + 1);
        const char* Ab = ldsb + cur * 24576;
        const char* Bb = Ab + 16384;
#pragma unroll
        for (int kk = 0; kk < 2; ++kk) {
            const int off = (kk * 64 + u * 16) ^ ((c & 7) << 4);
            bf16x8 af[4], bfr[2];
#pragma unroll
            for (int i = 0; i < 4; ++i)
                af[i] = *(const bf16x8*)(Ab + (mo + 16 * i + c) * 128 + off);
#pragma unroll
            for (int j = 0; j < 2; ++j)
                bfr[j] = *(const bf16x8*)(Bb + (no + 16 * j + c) * 128 + off);
#pragma unroll
            for (int i = 0; i < 4; ++i)
#pragma unroll
                for (int j = 0; j < 2; ++j)
                    acc[i][j] = __builtin_amdgcn_mfma_f32_16x16x32_bf16(af[i], bfr[j], acc[i][j], 0, 0, 0);
        }
        __syncthreads();
        cur ^= 1;
    }

    // 1/sqrt(48) * log2(e): scores land in log2 domain so attn can use raw v_exp_f32
    const float qscale = 0.14433756729740643f * 1.4426950408889634f;
#pragma unroll
    for (int i = 0; i < 4; ++i) {
#pragma unroll
        for (int j = 0; j < 2; ++j) {
            int n = n0 + no + 16 * j + c;        // region uniform per 16-wide subtile
            int mb = m0 + mo + 16 * i + 4 * u;
            int b = mb >> 11;
            int t0 = mb & 2047;
            if (n < 480) {                       // q or k: RoPE, 64-padded store
                int nn = (n < 384) ? n : n - 384;
                int h = nn / 48, d = nn - h * 48;
                int fi = d >> 1;
                float sgn = (d & 1) ? 1.0f : -1.0f;
                float scl = (n < 384) ? qscale : 1.0f;
                short* dst = (n < 384) ? qb : kb;
                size_t base = (n < 384)
                    ? ((size_t)(b * HQ_ + h) * T_ + t0) * 64 + d
                    : ((size_t)(b * HKV_ + h) * T_ + t0) * 64 + d;
#pragma unroll
                for (int r = 0; r < 4; ++r) {
                    float val = acc[i][j][r];
                    float part = __shfl_xor(val, 1);
                    float cs = ct[(t0 + r) * DH_ + fi], sn = st[(t0 + r) * DH_ + fi];
                    dst[base + (size_t)r * 64] = f2bf((val * cs + sgn * part * sn) * scl);
                }
            } else {                             // v: no rope, transposed store
                int nn = n - 480;
                int h = nn / 48, d = nn - h * 48;
                ushort4 pk;
                pk.x = (unsigned short)f2bf(acc[i][j][0]);
                pk.y = (unsigned short)f2bf(acc[i][j][1]);
                pk.z = (unsigned short)f2bf(acc[i][j][2]);
                pk.w = (unsigned short)f2bf(acc[i][j][3]);
                *(ushort4*)&vtb[((size_t)(b * HKV_ + h) * D_ + d) * T_ + t0] = pk;
            }
        }
    }
}

// ---------------- kernel 2: phase-specialized fused-qt flash attention -----
// R11 structure with the jt loop split into 4 statically-specialized phases:
//   phase1 jt<qt1        : UNIT_FULL(qs0)+UNIT_FULL(qs1)   (straight-line)
//   phase2 jt==qt1       : UNIT_FULL(qs0)+UNIT_DIAG(qs1)
//   phase3 qt1<jt<qt0    : UNIT_FULL(qs0)
//   phase4 jt==qt0       : UNIT_DIAG(qs0)
// R11 audit: VALUBusy 45% was ~5x the softmax math — runtime guards
// (mt<mtmax, qs-continue, diag&&) dominated. UNIT_FULL has literal bounds,
// no predicates. Math identical.

#define UNIT_FULL(QS) { \
_Pragma("unroll") \
for (int g = 0; g < 2; ++g) { \
    f32x4 s[4]; \
    __builtin_amdgcn_s_setprio(1); \
    _Pragma("unroll") \
    for (int mt = 0; mt < 4; ++mt) { \
        f32x4 a = {0.f, 0.f, 0.f, 0.f}; \
        a = __builtin_amdgcn_mfma_f32_16x16x32_bf16(klo[mt], qf0[QS][g], a, 0, 0, 0); \
        a = __builtin_amdgcn_mfma_f32_16x16x32_bf16(khi[mt], qf1[QS][g], a, 0, 0, 0); \
        s[mt] = a; \
    } \
    __builtin_amdgcn_s_setprio(0); \
    float mloc = max3f(max3f(s[0][0], s[0][1], s[0][2]), s[0][3], -1e30f); \
    mloc = max3f(max3f(s[1][0], s[1][1], s[1][2]), s[1][3], mloc); \
    mloc = max3f(max3f(s[2][0], s[2][1], s[2][2]), s[2][3], mloc); \
    mloc = max3f(max3f(s[3][0], s[3][1], s[3][2]), s[3][3], mloc); \
    mloc = fmaxf(mloc, __shfl_xor(mloc, 16)); \
    mloc = fmaxf(mloc, __shfl_xor(mloc, 32)); \
    if (__any(mloc > m_s[QS][g] + 8.0f)) { \
        float mnew = fmaxf(m_s[QS][g], mloc); \
        float alpha = exp2_fast(m_s[QS][g] - mnew); \
        m_s[QS][g] = mnew; \
        l_s[QS][g] *= alpha; \
        float a0 = __shfl(alpha, 4 * u + 0); \
        float a1 = __shfl(alpha, 4 * u + 1); \
        float a2 = __shfl(alpha, 4 * u + 2); \
        float a3 = __shfl(alpha, 4 * u + 3); \
        _Pragma("unroll") \
        for (int nt = 0; nt < 3; ++nt) { \
            o[QS][g][nt][0] *= a0; o[QS][g][nt][1] *= a1; \
            o[QS][g][nt][2] *= a2; o[QS][g][nt][3] *= a3; \
        } \
    } \
    bf16x4 pf[4]; \
    _Pragma("unroll") \
    for (int mt = 0; mt < 4; ++mt) { \
        float p0 = exp2_fast(s[mt][0] - m_s[QS][g]); \
        float p1 = exp2_fast(s[mt][1] - m_s[QS][g]); \
        float p2 = exp2_fast(s[mt][2] - m_s[QS][g]); \
        float p3 = exp2_fast(s[mt][3] - m_s[QS][g]); \
        l_s[QS][g] += (p0 + p1) + (p2 + p3); \
        union { unsigned u2[2]; bf16x4 v; } pk; \
        pk.u2[0] = cvt_pk_bf16(p0, p1); \
        pk.u2[1] = cvt_pk_bf16(p2, p3); \
        pf[mt] = pk.v; \
    } \
    __builtin_amdgcn_s_setprio(1); \
    _Pragma("unroll") \
    for (int k2 = 0; k2 < 4; ++k2) \
        _Pragma("unroll") \
        for (int nt = 0; nt < 3; ++nt) \
            o[QS][g][nt] = __builtin_amdgcn_mfma_f32_16x16x16bf16_1k(pf[k2], vf[nt][k2], o[QS][g][nt], 0, 0, 0); \
    __builtin_amdgcn_s_setprio(0); \
} }

#define UNIT_DIAG(QS) { \
const int mtw = w + 1; \
_Pragma("unroll") \
for (int g = 0; g < 2; ++g) { \
    f32x4 s[4]; \
    __builtin_amdgcn_s_setprio(1); \
    _Pragma("unroll") \
    for (int mt = 0; mt < 4; ++mt) { \
        if (mt < mtw) { \
            f32x4 a = {0.f, 0.f, 0.f, 0.f}; \
            a = __builtin_amdgcn_mfma_f32_16x16x32_bf16(klo[mt], qf0[QS][g], a, 0, 0, 0); \
            a = __builtin_amdgcn_mfma_f32_16x16x32_bf16(khi[mt], qf1[QS][g], a, 0, 0, 0); \
            if (mt == mtw - 1) { \
                _Pragma("unroll") \
                for (int r = 0; r < 4; ++r) \
                    a[r] = (4 * u + r > c) ? -1e30f : a[r]; \
            } \
            s[mt] = a; \
        } \
    } \
    __builtin_amdgcn_s_setprio(0); \
    float mloc = -1e30f; \
    _Pragma("unroll") \
    for (int mt = 0; mt < 4; ++mt) \
        if (mt < mtw) \
            mloc = max3f(max3f(s[mt][0], s[mt][1], s[mt][2]), s[mt][3], mloc); \
    mloc = fmaxf(mloc, __shfl_xor(mloc, 16)); \
    mloc = fmaxf(mloc, __shfl_xor(mloc, 32)); \
    if (__any(mloc > m_s[QS][g] + 8.0f)) { \
        float mnew = fmaxf(m_s[QS][g], mloc); \
        float alpha = exp2_fast(m_s[QS][g] - mnew); \
        m_s[QS][g] = mnew; \
        l_s[QS][g] *= alpha; \
        float a0 = __shfl(alpha, 4 * u + 0); \
        float a1 = __shfl(alpha, 4 * u + 1); \
        float a2 = __shfl(alpha, 4 * u + 2); \
        float a3 = __shfl(alpha, 4 * u + 3); \
        _Pragma("unroll") \
        for (int nt = 0; nt < 3; ++nt) { \
            o[QS][g][nt][0] *= a0; o[QS][g][nt][1] *= a1; \
            o[QS][g][nt][2] *= a2; o[QS][g][nt][3] *= a3; \
        } \
    } \
    bf16x4 pf[4]; \
    _Pragma("unroll") \
    for (int mt = 0; mt < 4; ++mt) { \
        if (mt < mtw) { \
            float p0 = exp2_fast(s[mt][0] - m_s[QS][g]); \
            float p1 = exp2_fast(s[mt][1] - m_s[QS][g]); \
            float p2 = exp2_fast(s[mt][2] - m_s[QS][g]); \
            float p3 = exp2_fast(s[mt][3] - m_s[QS][g]); \
            l_s[QS][g] += (p0 + p1) + (p2 + p3); \
            union { unsigned u2[2]; bf16x4 v; } pk; \
            pk.u2[0] = cvt_pk_bf16(p0, p1); \
            pk.u2[1] = cvt_pk_bf16(p2, p3); \
            pf[mt] = pk.v; \
        } \
    } \
    __builtin_amdgcn_s_setprio(1); \
    _Pragma("unroll") \
    for (int k2 = 0; k2 < 4; ++k2) { \
        if (k2 < mtw) { \
            _Pragma("unroll") \
            for (int nt = 0; nt < 3; ++nt) \
                o[QS][g][nt] = __builtin_amdgcn_mfma_f32_16x16x16bf16_1k(pf[k2], vf[nt][k2], o[QS][g][nt], 0, 0, 0); \
        } \
    } \
    __builtin_amdgcn_s_setprio(0); \
} }

#define FRAGS_FULL() \
    _Pragma("unroll") \
    for (int mt = 0; mt < 4; ++mt) { \
        klo[mt] = *(const bf16x8*)(kbuf + mt * 2048 + c * 128 + okl); \
        khi[mt] = *(const bf16x8*)(kbuf + mt * 2048 + c * 128 + okh); \
    } \
    _Pragma("unroll") \
    for (int nt = 0; nt < 3; ++nt) \
        _Pragma("unroll") \
        for (int k2 = 0; k2 < 4; ++k2) \
            vf[nt][k2] = *(const bf16x4*)(vbuf + nt * 2048 + c * 128 + (((k2 * 32) | (u * 8)) ^ mk));

__global__ __launch_bounds__(256, 2) void attn_kernel(
    const short* __restrict__ qb, const short* __restrict__ kb,
    const short* __restrict__ vtb, short* __restrict__ aob)
{
    __shared__ __align__(16) short lds_s[14336];   // 2 x (8KB K + 6KB V)
    const int tid = threadIdx.x;
    const int x  = blockIdx.x;          // 0..15
    const int hk = blockIdx.y >> 1;     // 0..1
    const int gp = blockIdx.y & 1;      // head pair within group
    const int b  = blockIdx.z;
    const int lane = tid & 63;
    const int w = tid >> 6;             // q-subtile: q rows 16w..16w+15
    const int c = lane & 15;
    const int u = lane >> 4;
    const int qt0 = 31 - x;             // 16..31
    const int qt1 = x;                  // 0..15  (qt1 < qt0 always)

    const char* kg = (const char*)kb  + (size_t)(b * HKV_ + hk) * T_ * 128;   // K rows 128B
    const char* vg = (const char*)vtb + (size_t)(b * HKV_ + hk) * D_ * T_ * 2; // V^T row stride 4096B

    const int swz  = (lane ^ ((lane >> 3) & 7)) << 4;   // stage-side src swizzle
    const int vrow = lane >> 3;                          // 0..7
    const int voff = swz & 127;                          // within-row byte pos

    const int mk  = (c & 7) << 4;
    const int okl = (u * 16) ^ mk;            // K d 0..31 fragment
    const int okh = (64 | (u * 16)) ^ mk;     // K d 32..63 fragment

    auto stage = [&](int bsel, int jt) {
        char* dst = (char*)lds_s + bsel * 14336;
        const char* kt = kg + (size_t)jt * 8192;
        gld16(kt + (2 * w) * 1024 + swz,     dst + (2 * w) * 1024);
        gld16(kt + (2 * w + 1) * 1024 + swz, dst + (2 * w + 1) * 1024);
        if (w < 3) {
            const char* vt = vg + (size_t)jt * 128;
            gld16(vt + (size_t)(16 * w + vrow) * 4096 + voff,
                  dst + 8192 + (2 * w) * 1024);
            gld16(vt + (size_t)(16 * w + 8 + vrow) * 4096 + voff,
                  dst + 8192 + (2 * w + 1) * 1024);
        }
    };

    // Q fragments for both qt-tiles, both heads
    bf16x8 qf0[2][2], qf1[2][2];        // [qs][g]
#pragma unroll
    for (int qs = 0; qs < 2; ++qs) {
        const int qt = qs ? qt1 : qt0;
#pragma unroll
        for (int g = 0; g < 2; ++g) {
            int h = hk * 4 + gp * 2 + g;
            const short* qp = qb + ((size_t)(b * HQ_ + h) * T_ + qt * 64 + 16 * w + c) * 64;
            qf0[qs][g] = *(const bf16x8*)(qp + 8 * u);          // d 0..31
            qf1[qs][g] = *(const bf16x8*)(qp + 32 + 8 * u);     // d 32..63 (pad=0)
        }
    }
    float m_s[2][2] = { { -1e30f, -1e30f }, { -1e30f, -1e30f } };
    float l_s[2][2] = {};               // per-lane partials (reduced in epilogue)
    f32x4 o[2][2][3] = {};

    int cur = 0;
    stage(0, 0);
    __syncthreads();

    int jt = 0;
    // ---- phase 1: jt < qt1 — both Q-tiles, full, no diagonal ----
#pragma unroll 1
    for (; jt < qt1; ++jt) {
        stage(cur ^ 1, jt + 1);
        const char* kbuf = (const char*)lds_s + cur * 14336;
        const char* vbuf = kbuf + 8192;
        bf16x8 klo[4], khi[4];
        bf16x4 vf[3][4];
        FRAGS_FULL();
        UNIT_FULL(0);
        UNIT_FULL(1);
        __syncthreads();
        cur ^= 1;
    }
    // ---- phase 2: jt == qt1 — qs0 full, qs1 diagonal ----
    {
        stage(cur ^ 1, jt + 1);                 // qt1+1 <= qt0 always
        const char* kbuf = (const char*)lds_s + cur * 14336;
        const char* vbuf = kbuf + 8192;
        bf16x8 klo[4], khi[4];
        bf16x4 vf[3][4];
        FRAGS_FULL();
        UNIT_FULL(0);
        UNIT_DIAG(1);
        __syncthreads();
        cur ^= 1;
        ++jt;
    }
    // ---- phase 3: qt1 < jt < qt0 — qs0 only, full ----
#pragma unroll 1
    for (; jt < qt0; ++jt) {
        stage(cur ^ 1, jt + 1);
        const char* kbuf = (const char*)lds_s + cur * 14336;
        const char* vbuf = kbuf + 8192;
        bf16x8 klo[4], khi[4];
        bf16x4 vf[3][4];
        FRAGS_FULL();
        UNIT_FULL(0);
        __syncthreads();
        cur ^= 1;
    }
    // ---- phase 4: jt == qt0 — qs0 diagonal (no stage, no barrier) ----
    {
        const char* kbuf = (const char*)lds_s + cur * 14336;
        const char* vbuf = kbuf + 8192;
        const int mtw = w + 1;
        bf16x8 klo[4], khi[4];
        bf16x4 vf[3][4];
#pragma unroll
        for (int mt = 0; mt < 4; ++mt) {
            if (mt < mtw) {
                klo[mt] = *(const bf16x8*)(kbuf + mt * 2048 + c * 128 + okl);
                khi[mt] = *(const bf16x8*)(kbuf + mt * 2048 + c * 128 + okh);
            }
        }
#pragma unroll
        for (int nt = 0; nt < 3; ++nt)
#pragma unroll
            for (int k2 = 0; k2 < 4; ++k2)
                if (k2 < mtw)
                    vf[nt][k2] = *(const bf16x4*)(vbuf + nt * 2048 + c * 128 +
                                                  (((k2 * 32) | (u * 8)) ^ mk));
        UNIT_DIAG(0);
    }

    // epilogue: deferred l-reduction, then O writeback
#pragma unroll
    for (int qs = 0; qs < 2; ++qs) {
        const int qt = qs ? qt1 : qt0;
#pragma unroll
        for (int g = 0; g < 2; ++g) {
            int h = hk * 4 + gp * 2 + g;
            float lt = l_s[qs][g];
            lt += __shfl_xor(lt, 16);
            lt += __shfl_xor(lt, 32);           // full sum for q=c, replicated
            float li = 1.0f / lt;
            float l0 = __shfl(li, 4 * u + 0);
            float l1 = __shfl(li, 4 * u + 1);
            float l2 = __shfl(li, 4 * u + 2);
            float l3 = __shfl(li, 4 * u + 3);
            float lr[4] = { l0, l1, l2, l3 };
#pragma unroll
            for (int nt = 0; nt < 3; ++nt)
#pragma unroll
                for (int r = 0; r < 4; ++r) {
                    int t = qt * 64 + 16 * w + 4 * u + r;
                    aob[((size_t)b * T_ + t) * NE_ + h * D_ + 16 * nt + c] =
                        f2bf(o[qs][g][nt][r] * lr[r]);
                }
        }
    }
}

// ---------------- kernel 3: out projection MFMA + bias ----------------
__global__ __launch_bounds__(256) void out_gemm_kernel(
    const short* __restrict__ aob, const short* __restrict__ wot,
    const float* __restrict__ bias, float* __restrict__ out)
{
    __shared__ __align__(16) char ldsb[49152];
    const int tid = threadIdx.x;
    const int n0 = blockIdx.x * 64;     // 6 tiles
    const int m0 = blockIdx.y * 128;    // 128 tiles
    const int lane = tid & 63, w = tid >> 6;
    const int c = lane & 15, u = lane >> 4;
    const int mo = (w & 1) * 64, no = (w >> 1) * 32;
    const int lrow = lane >> 3;
    const int lcol = (((lane & 7) ^ lrow) << 4);
    f32x4 acc[4][2] = {};

    auto stage = [&](int bsel, int t) {
        char* dst = ldsb + bsel * 24576;
        const char* Ag = (const char*)aob + (size_t)(m0 + w * 32 + lrow) * 768 + t * 128 + lcol;
#pragma unroll
        for (int p = 0; p < 4; ++p)
            gld16(Ag + p * 8 * 768, dst + w * 4096 + p * 1024);
        const char* Bg = (const char*)wot + (size_t)(n0 + w * 16 + lrow) * 768 + t * 128 + lcol;
#pragma unroll
        for (int p = 0; p < 2; ++p)
            gld16(Bg + p * 8 * 768, dst + 16384 + w * 2048 + p * 1024);
    };

    stage(0, 0);
    __syncthreads();
    int cur = 0;
#pragma unroll 1
    for (int t = 0; t < 6; ++t) {
        if (t < 5) stage(cur ^ 1, t + 1);
        const char* Ab = ldsb + cur * 24576;
        const char* Bb = Ab + 16384;
#pragma unroll
        for (int kk = 0; kk < 2; ++kk) {
            const int off = (kk * 64 + u * 16) ^ ((c & 7) << 4);
            bf16x8 af[4], bfr[2];
#pragma unroll
            for (int i = 0; i < 4; ++i)
                af[i] = *(const bf16x8*)(Ab + (mo + 16 * i + c) * 128 + off);
#pragma unroll
            for (int j = 0; j < 2; ++j)
                bfr[j] = *(const bf16x8*)(Bb + (no + 16 * j + c) * 128 + off);
#pragma unroll
            for (int i = 0; i < 4; ++i)
#pragma unroll
                for (int j = 0; j < 2; ++j)
                    acc[i][j] = __builtin_amdgcn_mfma_f32_16x16x32_bf16(af[i], bfr[j], acc[i][j], 0, 0, 0);
        }
        __syncthreads();
        cur ^= 1;
    }

#pragma unroll
    for (int i = 0; i < 4; ++i) {
#pragma unroll
        for (int j = 0; j < 2; ++j) {
            int n = n0 + no + 16 * j + c;
            int mb = m0 + mo + 16 * i + 4 * u;
            float bv = bias[n];
#pragma unroll
            for (int r = 0; r < 4; ++r)
                out[(size_t)(mb + r) * 384 + n] = acc[i][j][r] + bv;
        }
    }
}

// ---------------- launcher ----------------
extern "C" void kernel_launch(void* const* d_in, const int* in_sizes, int n_in,
                              void* d_out, int out_size, void* d_ws, size_t ws_size,
                              hipStream_t stream) {
    const float* x  = (const float*)d_in[0];
    const float* wq = (const float*)d_in[1];
    const float* wk = (const float*)d_in[2];
    const float* wv = (const float*)d_in[3];
    const float* wo = (const float*)d_in[4];
    const float* bo = (const float*)d_in[5];
    float* out = (float*)d_out;

    float* ct  = (float*)d_ws;                       // 49152 f32
    float* st  = ct + 49152;                         // 49152 f32
    short* xb  = (short*)(st + 49152);               // 16384*384
    short* wt  = xb  + (size_t)16384 * 384;          // 576*384
    short* wot = wt  + (size_t)576 * 384;            // 384*384
    short* qb  = wot + (size_t)384 * 384;            // 8*8*2048*64 (d-padded)
    short* kb  = qb  + (size_t)B_ * HQ_  * T_ * 64;  // 8*2*2048*64 (d-padded)
    short* vtb = kb  + (size_t)B_ * HKV_ * T_ * 64;  // 8*2*48*2048 (transposed)
    short* aob = vtb + (size_t)B_ * HKV_ * D_ * T_;  // 16384*384
    // total ~50.4 MB

    hipLaunchKernelGGL(prep_kernel, dim3(9056), dim3(256), 0, stream,
                       x, wq, wk, wv, wo, xb, wt, wot, ct, st, qb);
    hipLaunchKernelGGL(qkv_gemm_kernel, dim3(9, 128), dim3(256), 0, stream,
                       xb, wt, ct, st, qb, kb, vtb);
    hipLaunchKernelGGL(attn_kernel, dim3(16, 4, 8), dim3(256), 0, stream,
                       qb, kb, vtb, aob);
    hipLaunchKernelGGL(out_gemm_kernel, dim3(6, 128), dim3(256), 0, stream,
                       aob, wot, bo, out);
}

// Round 19
// 177.433 us; speedup vs baseline: 1.3752x; 1.0448x over previous
//
#include <hip/hip_runtime.h>
#include <math.h>

#define B_   8
#define T_   2048
#define NE_  384
#define HQ_  8
#define HKV_ 2
#define D_   48
#define DH_  24   // D/2

typedef __attribute__((ext_vector_type(8))) short bf16x8;
typedef __attribute__((ext_vector_type(4))) short bf16x4;
typedef __attribute__((ext_vector_type(4))) float f32x4;

static __device__ __forceinline__ short f2bf(float f) {
    union { float f; unsigned u; } v; v.f = f;
    unsigned r = (v.u + 0x7fffu + ((v.u >> 16) & 1u)) >> 16;
    return (short)r;
}

// native 2^x (scores are pre-scaled by log2(e) in the QKV epilogue)
static __device__ __forceinline__ float exp2_fast(float x) {
    float r;
    asm("v_exp_f32 %0, %1" : "=v"(r) : "v"(x));
    return r;
}
// packed f32x2 -> bf16x2 RNE conversion, one instruction
static __device__ __forceinline__ unsigned cvt_pk_bf16(float lo, float hi) {
    unsigned r;
    asm("v_cvt_pk_bf16_f32 %0, %1, %2" : "=v"(r) : "v"(lo), "v"(hi));
    return r;
}
static __device__ __forceinline__ float max3f(float a, float b, float c) {
    float r;
    asm("v_max3_f32 %0, %1, %2, %3" : "=v"(r) : "v"(a), "v"(b), "v"(c));
    return r;
}
// async global->LDS DMA, 16B per lane (dest = wave-uniform base + lane*16)
static __device__ __forceinline__ void gld16(const void* g, void* l) {
    __builtin_amdgcn_global_load_lds(
        (const __attribute__((address_space(1))) unsigned int*)g,
        (__attribute__((address_space(3))) unsigned int*)l,
        16, 0, 0);
}

// ---------------- kernel 0: prep (convert + transpose + rope + pad-zero) ---
__global__ __launch_bounds__(256) void prep_kernel(
    const float* __restrict__ x, const float* __restrict__ wq,
    const float* __restrict__ wk, const float* __restrict__ wv,
    const float* __restrict__ wo,
    short* __restrict__ xb, short* __restrict__ wt, short* __restrict__ wot,
    float* __restrict__ ct, float* __restrict__ st,
    short* __restrict__ qb)
{
    const int bid = blockIdx.x, tid = threadIdx.x;
    if (bid < 6144) {
        int i = bid * 256 + tid;                 // float4 index, 1572864 total
        float4 v = ((const float4*)x)[i];
        bf16x4 o = { f2bf(v.x), f2bf(v.y), f2bf(v.z), f2bf(v.w) };
        *(bf16x4*)&xb[(size_t)i * 4] = o;
    } else if (bid < 7008) {
        int e = (bid - 6144) * 256 + tid;        // < 221184
        int n = e / 384, k = e - n * 384;
        float s = (n < 384) ? wq[(size_t)k * 384 + n]
                : (n < 480) ? wk[(size_t)k * 96 + (n - 384)]
                            : wv[(size_t)k * 96 + (n - 480)];
        wt[e] = f2bf(s);
    } else if (bid < 7584) {
        int e = (bid - 7008) * 256 + tid;        // < 147456
        int n = e / 384, k = e - n * 384;
        wot[e] = f2bf(wo[(size_t)k * 384 + n]);
    } else if (bid < 7776) {
        int i = (bid - 7584) * 256 + tid;        // < 49152
        int t = i / DH_, j = i - t * DH_;
        float inv = powf(10000.0f, -(float)(2 * j) / (float)D_);
        float ang = (float)t * inv;
        float sv, cv;
        __sincosf(ang, &sv, &cv);
        ct[i] = cv;
        st[i] = sv;
    } else {
        // zero d-pad cols 48..63 of qb (131072 rows) + kb (32768 rows, adjacent)
        int i = (bid - 7776) * 256 + tid;        // < 327680
        int row = i >> 1, half = i & 1;
        bf16x8 z = {};
        *(bf16x8*)&qb[(size_t)row * 64 + 48 + half * 8] = z;
    }
}

// ---------------- kernel 1: QKV MFMA GEMM + fused RoPE ----------
__global__ __launch_bounds__(256) void qkv_gemm_kernel(
    const short* __restrict__ xb, const short* __restrict__ wt,
    const float* __restrict__ ct, const float* __restrict__ st,
    short* __restrict__ qb, short* __restrict__ kb, short* __restrict__ vtb)
{
    __shared__ __align__(16) char ldsb[49152];   // 2 x (A 16KB + B 8KB)
    const int tid = threadIdx.x;
    const int n0 = blockIdx.x * 64;     // 9 tiles
    const int m0 = blockIdx.y * 128;    // 128 tiles
    const int lane = tid & 63, w = tid >> 6;
    const int c = lane & 15, u = lane >> 4;
    const int mo = (w & 1) * 64, no = (w >> 1) * 32;
    const int lrow = lane >> 3;                          // 0..7 within 1KB chunk
    const int lcol = (((lane & 7) ^ lrow) << 4);         // swizzled src byte in 128B row
    f32x4 acc[4][2] = {};

    auto stage = [&](int bsel, int t) {
        char* dst = ldsb + bsel * 24576;
        const char* Ag = (const char*)xb + (size_t)(m0 + w * 32 + lrow) * 768 + t * 128 + lcol;
#pragma unroll
        for (int p = 0; p < 4; ++p)
            gld16(Ag + p * 8 * 768, dst + w * 4096 + p * 1024);
        const char* Bg = (const char*)wt + (size_t)(n0 + w * 16 + lrow) * 768 + t * 128 + lcol;
#pragma unroll
        for (int p = 0; p < 2; ++p)
            gld16(Bg + p * 8 * 768, dst + 16384 + w * 2048 + p * 1024);
    };

    stage(0, 0);
    __syncthreads();
    int cur = 0;
#pragma unroll 1
    for (int t = 0; t < 6; ++t) {
        if (t < 5) stage(cur ^ 1, t + 1);
        const char* Ab = ldsb + cur * 24576;
        const char* Bb = Ab + 16384;
#pragma unroll
        for (int kk = 0; kk < 2; ++kk) {
            const int off = (kk * 64 + u * 16) ^ ((c & 7) << 4);
            bf16x8 af[4], bfr[2];
#pragma unroll
            for (int i = 0; i < 4; ++i)
                af[i] = *(const bf16x8*)(Ab + (mo + 16 * i + c) * 128 + off);
#pragma unroll
            for (int j = 0; j < 2; ++j)
                bfr[j] = *(const bf16x8*)(Bb + (no + 16 * j + c) * 128 + off);
#pragma unroll
            for (int i = 0; i < 4; ++i)
#pragma unroll
                for (int j = 0; j < 2; ++j)
                    acc[i][j] = __builtin_amdgcn_mfma_f32_16x16x32_bf16(af[i], bfr[j], acc[i][j], 0, 0, 0);
        }
        __syncthreads();
        cur ^= 1;
    }

    // 1/sqrt(48) * log2(e): scores land in log2 domain so attn can use raw v_exp_f32
    const float qscale = 0.14433756729740643f * 1.4426950408889634f;
#pragma unroll
    for (int i = 0; i < 4; ++i) {
#pragma unroll
        for (int j = 0; j < 2; ++j) {
            int n = n0 + no + 16 * j + c;        // region uniform per 16-wide subtile
            int mb = m0 + mo + 16 * i + 4 * u;
            int b = mb >> 11;
            int t0 = mb & 2047;
            if (n < 480) {                       // q or k: RoPE, 64-padded store
                int nn = (n < 384) ? n : n - 384;
                int h = nn / 48, d = nn - h * 48;
                int fi = d >> 1;
                float sgn = (d & 1) ? 1.0f : -1.0f;
                float scl = (n < 384) ? qscale : 1.0f;
                short* dst = (n < 384) ? qb : kb;
                size_t base = (n < 384)
                    ? ((size_t)(b * HQ_ + h) * T_ + t0) * 64 + d
                    : ((size_t)(b * HKV_ + h) * T_ + t0) * 64 + d;
#pragma unroll
                for (int r = 0; r < 4; ++r) {
                    float val = acc[i][j][r];
                    float part = __shfl_xor(val, 1);
                    float cs = ct[(t0 + r) * DH_ + fi], sn = st[(t0 + r) * DH_ + fi];
                    dst[base + (size_t)r * 64] = f2bf((val * cs + sgn * part * sn) * scl);
                }
            } else {                             // v: no rope, transposed store
                int nn = n - 480;
                int h = nn / 48, d = nn - h * 48;
                ushort4 pk;
                pk.x = (unsigned short)f2bf(acc[i][j][0]);
                pk.y = (unsigned short)f2bf(acc[i][j][1]);
                pk.z = (unsigned short)f2bf(acc[i][j][2]);
                pk.w = (unsigned short)f2bf(acc[i][j][3]);
                *(ushort4*)&vtb[((size_t)(b * HKV_ + h) * D_ + d) * T_ + t0] = pk;
            }
        }
    }
}

// ---------------- kernel 2: phase-specialized fused-qt flash attention -----
// R13 + vote-only defer-max check: __any(local_max > m+8) is logically
// identical to __any(reduced_max > m+8) — both <=> global max exceeds — so
// the 2 cross-lane __shfl_xor (DS latency, serialized on the softmax
// critical path) move INSIDE the rare branch. Common path: QK -> local max3
// chain -> s_vote -> exp2, zero DS ops. Math bit-identical.

#define UNIT_FULL(QS) { \
_Pragma("unroll") \
for (int g = 0; g < 2; ++g) { \
    f32x4 s[4]; \
    __builtin_amdgcn_s_setprio(1); \
    _Pragma("unroll") \
    for (int mt = 0; mt < 4; ++mt) { \
        f32x4 a = {0.f, 0.f, 0.f, 0.f}; \
        a = __builtin_amdgcn_mfma_f32_16x16x32_bf16(klo[mt], qf0[QS][g], a, 0, 0, 0); \
        a = __builtin_amdgcn_mfma_f32_16x16x32_bf16(khi[mt], qf1[QS][g], a, 0, 0, 0); \
        s[mt] = a; \
    } \
    __builtin_amdgcn_s_setprio(0); \
    float mloc = max3f(max3f(s[0][0], s[0][1], s[0][2]), s[0][3], -1e30f); \
    mloc = max3f(max3f(s[1][0], s[1][1], s[1][2]), s[1][3], mloc); \
    mloc = max3f(max3f(s[2][0], s[2][1], s[2][2]), s[2][3], mloc); \
    mloc = max3f(max3f(s[3][0], s[3][1], s[3][2]), s[3][3], mloc); \
    if (__any(mloc > m_s[QS][g] + 8.0f)) { \
        mloc = fmaxf(mloc, __shfl_xor(mloc, 16)); \
        mloc = fmaxf(mloc, __shfl_xor(mloc, 32)); \
        float mnew = fmaxf(m_s[QS][g], mloc); \
        float alpha = exp2_fast(m_s[QS][g] - mnew); \
        m_s[QS][g] = mnew; \
        l_s[QS][g] *= alpha; \
        float a0 = __shfl(alpha, 4 * u + 0); \
        float a1 = __shfl(alpha, 4 * u + 1); \
        float a2 = __shfl(alpha, 4 * u + 2); \
        float a3 = __shfl(alpha, 4 * u + 3); \
        _Pragma("unroll") \
        for (int nt = 0; nt < 3; ++nt) { \
            o[QS][g][nt][0] *= a0; o[QS][g][nt][1] *= a1; \
            o[QS][g][nt][2] *= a2; o[QS][g][nt][3] *= a3; \
        } \
    } \
    bf16x4 pf[4]; \
    _Pragma("unroll") \
    for (int mt = 0; mt < 4; ++mt) { \
        float p0 = exp2_fast(s[mt][0] - m_s[QS][g]); \
        float p1 = exp2_fast(s[mt][1] - m_s[QS][g]); \
        float p2 = exp2_fast(s[mt][2] - m_s[QS][g]); \
        float p3 = exp2_fast(s[mt][3] - m_s[QS][g]); \
        l_s[QS][g] += (p0 + p1) + (p2 + p3); \
        union { unsigned u2[2]; bf16x4 v; } pk; \
        pk.u2[0] = cvt_pk_bf16(p0, p1); \
        pk.u2[1] = cvt_pk_bf16(p2, p3); \
        pf[mt] = pk.v; \
    } \
    __builtin_amdgcn_s_setprio(1); \
    _Pragma("unroll") \
    for (int k2 = 0; k2 < 4; ++k2) \
        _Pragma("unroll") \
        for (int nt = 0; nt < 3; ++nt) \
            o[QS][g][nt] = __builtin_amdgcn_mfma_f32_16x16x16bf16_1k(pf[k2], vf[nt][k2], o[QS][g][nt], 0, 0, 0); \
    __builtin_amdgcn_s_setprio(0); \
} }

#define UNIT_DIAG(QS) { \
const int mtw = w + 1; \
_Pragma("unroll") \
for (int g = 0; g < 2; ++g) { \
    f32x4 s[4]; \
    __builtin_amdgcn_s_setprio(1); \
    _Pragma("unroll") \
    for (int mt = 0; mt < 4; ++mt) { \
        if (mt < mtw) { \
            f32x4 a = {0.f, 0.f, 0.f, 0.f}; \
            a = __builtin_amdgcn_mfma_f32_16x16x32_bf16(klo[mt], qf0[QS][g], a, 0, 0, 0); \
            a = __builtin_amdgcn_mfma_f32_16x16x32_bf16(khi[mt], qf1[QS][g], a, 0, 0, 0); \
            if (mt == mtw - 1) { \
                _Pragma("unroll") \
                for (int r = 0; r < 4; ++r) \
                    a[r] = (4 * u + r > c) ? -1e30f : a[r]; \
            } \
            s[mt] = a; \
        } \
    } \
    __builtin_amdgcn_s_setprio(0); \
    float mloc = -1e30f; \
    _Pragma("unroll") \
    for (int mt = 0; mt < 4; ++mt) \
        if (mt < mtw) \
            mloc = max3f(max3f(s[mt][0], s[mt][1], s[mt][2]), s[mt][3], mloc); \
    if (__any(mloc > m_s[QS][g] + 8.0f)) { \
        mloc = fmaxf(mloc, __shfl_xor(mloc, 16)); \
        mloc = fmaxf(mloc, __shfl_xor(mloc, 32)); \
        float mnew = fmaxf(m_s[QS][g], mloc); \
        float alpha = exp2_fast(m_s[QS][g] - mnew); \
        m_s[QS][g] = mnew; \
        l_s[QS][g] *= alpha; \
        float a0 = __shfl(alpha, 4 * u + 0); \
        float a1 = __shfl(alpha, 4 * u + 1); \
        float a2 = __shfl(alpha, 4 * u + 2); \
        float a3 = __shfl(alpha, 4 * u + 3); \
        _Pragma("unroll") \
        for (int nt = 0; nt < 3; ++nt) { \
            o[QS][g][nt][0] *= a0; o[QS][g][nt][1] *= a1; \
            o[QS][g][nt][2] *= a2; o[QS][g][nt][3] *= a3; \
        } \
    } \
    bf16x4 pf[4]; \
    _Pragma("unroll") \
    for (int mt = 0; mt < 4; ++mt) { \
        if (mt < mtw) { \
            float p0 = exp2_fast(s[mt][0] - m_s[QS][g]); \
            float p1 = exp2_fast(s[mt][1] - m_s[QS][g]); \
            float p2 = exp2_fast(s[mt][2] - m_s[QS][g]); \
            float p3 = exp2_fast(s[mt][3] - m_s[QS][g]); \
            l_s[QS][g] += (p0 + p1) + (p2 + p3); \
            union { unsigned u2[2]; bf16x4 v; } pk; \
            pk.u2[0] = cvt_pk_bf16(p0, p1); \
            pk.u2[1] = cvt_pk_bf16(p2, p3); \
            pf[mt] = pk.v; \
        } \
    } \
    __builtin_amdgcn_s_setprio(1); \
    _Pragma("unroll") \
    for (int k2 = 0; k2 < 4; ++k2) { \
        if (k2 < mtw) { \
            _Pragma("unroll") \
            for (int nt = 0; nt < 3; ++nt) \
                o[QS][g][nt] = __builtin_amdgcn_mfma_f32_16x16x16bf16_1k(pf[k2], vf[nt][k2], o[QS][g][nt], 0, 0, 0); \
        } \
    } \
    __builtin_amdgcn_s_setprio(0); \
} }

#define FRAGS_FULL() \
    _Pragma("unroll") \
    for (int mt = 0; mt < 4; ++mt) { \
        klo[mt] = *(const bf16x8*)(kbuf + mt * 2048 + c * 128 + okl); \
        khi[mt] = *(const bf16x8*)(kbuf + mt * 2048 + c * 128 + okh); \
    } \
    _Pragma("unroll") \
    for (int nt = 0; nt < 3; ++nt) \
        _Pragma("unroll") \
        for (int k2 = 0; k2 < 4; ++k2) \
            vf[nt][k2] = *(const bf16x4*)(vbuf + nt * 2048 + c * 128 + (((k2 * 32) | (u * 8)) ^ mk));

__global__ __launch_bounds__(256, 2) void attn_kernel(
    const short* __restrict__ qb, const short* __restrict__ kb,
    const short* __restrict__ vtb, short* __restrict__ aob)
{
    __shared__ __align__(16) short lds_s[14336];   // 2 x (8KB K + 6KB V)
    const int tid = threadIdx.x;
    const int x  = blockIdx.x;          // 0..15
    const int hk = blockIdx.y >> 1;     // 0..1
    const int gp = blockIdx.y & 1;      // head pair within group
    const int b  = blockIdx.z;
    const int lane = tid & 63;
    const int w = tid >> 6;             // q-subtile: q rows 16w..16w+15
    const int c = lane & 15;
    const int u = lane >> 4;
    const int qt0 = 31 - x;             // 16..31
    const int qt1 = x;                  // 0..15  (qt1 < qt0 always)

    const char* kg = (const char*)kb  + (size_t)(b * HKV_ + hk) * T_ * 128;   // K rows 128B
    const char* vg = (const char*)vtb + (size_t)(b * HKV_ + hk) * D_ * T_ * 2; // V^T row stride 4096B

    const int swz  = (lane ^ ((lane >> 3) & 7)) << 4;   // stage-side src swizzle
    const int vrow = lane >> 3;                          // 0..7
    const int voff = swz & 127;                          // within-row byte pos

    const int mk  = (c & 7) << 4;
    const int okl = (u * 16) ^ mk;            // K d 0..31 fragment
    const int okh = (64 | (u * 16)) ^ mk;     // K d 32..63 fragment

    auto stage = [&](int bsel, int jt) {
        char* dst = (char*)lds_s + bsel * 14336;
        const char* kt = kg + (size_t)jt * 8192;
        gld16(kt + (2 * w) * 1024 + swz,     dst + (2 * w) * 1024);
        gld16(kt + (2 * w + 1) * 1024 + swz, dst + (2 * w + 1) * 1024);
        if (w < 3) {
            const char* vt = vg + (size_t)jt * 128;
            gld16(vt + (size_t)(16 * w + vrow) * 4096 + voff,
                  dst + 8192 + (2 * w) * 1024);
            gld16(vt + (size_t)(16 * w + 8 + vrow) * 4096 + voff,
                  dst + 8192 + (2 * w + 1) * 1024);
        }
    };

    // Q fragments for both qt-tiles, both heads
    bf16x8 qf0[2][2], qf1[2][2];        // [qs][g]
#pragma unroll
    for (int qs = 0; qs < 2; ++qs) {
        const int qt = qs ? qt1 : qt0;
#pragma unroll
        for (int g = 0; g < 2; ++g) {
            int h = hk * 4 + gp * 2 + g;
            const short* qp = qb + ((size_t)(b * HQ_ + h) * T_ + qt * 64 + 16 * w + c) * 64;
            qf0[qs][g] = *(const bf16x8*)(qp + 8 * u);          // d 0..31
            qf1[qs][g] = *(const bf16x8*)(qp + 32 + 8 * u);     // d 32..63 (pad=0)
        }
    }
    float m_s[2][2] = { { -1e30f, -1e30f }, { -1e30f, -1e30f } };
    float l_s[2][2] = {};               // per-lane partials (reduced in epilogue)
    f32x4 o[2][2][3] = {};

    int cur = 0;
    stage(0, 0);
    __syncthreads();

    int jt = 0;
    // ---- phase 1: jt < qt1 — both Q-tiles, full, no diagonal ----
#pragma unroll 1
    for (; jt < qt1; ++jt) {
        stage(cur ^ 1, jt + 1);
        const char* kbuf = (const char*)lds_s + cur * 14336;
        const char* vbuf = kbuf + 8192;
        bf16x8 klo[4], khi[4];
        bf16x4 vf[3][4];
        FRAGS_FULL();
        UNIT_FULL(0);
        UNIT_FULL(1);
        __syncthreads();
        cur ^= 1;
    }
    // ---- phase 2: jt == qt1 — qs0 full, qs1 diagonal ----
    {
        stage(cur ^ 1, jt + 1);                 // qt1+1 <= qt0 always
        const char* kbuf = (const char*)lds_s + cur * 14336;
        const char* vbuf = kbuf + 8192;
        bf16x8 klo[4], khi[4];
        bf16x4 vf[3][4];
        FRAGS_FULL();
        UNIT_FULL(0);
        UNIT_DIAG(1);
        __syncthreads();
        cur ^= 1;
        ++jt;
    }
    // ---- phase 3: qt1 < jt < qt0 — qs0 only, full ----
#pragma unroll 1
    for (; jt < qt0; ++jt) {
        stage(cur ^ 1, jt + 1);
        const char* kbuf = (const char*)lds_s + cur * 14336;
        const char* vbuf = kbuf + 8192;
        bf16x8 klo[4], khi[4];
        bf16x4 vf[3][4];
        FRAGS_FULL();
        UNIT_FULL(0);
        __syncthreads();
        cur ^= 1;
    }
    // ---- phase 4: jt == qt0 — qs0 diagonal (no stage, no barrier) ----
    {
        const char* kbuf = (const char*)lds_s + cur * 14336;
        const char* vbuf = kbuf + 8192;
        const int mtw = w + 1;
        bf16x8 klo[4], khi[4];
        bf16x4 vf[3][4];
#pragma unroll
        for (int mt = 0; mt < 4; ++mt) {
            if (mt < mtw) {
                klo[mt] = *(const bf16x8*)(kbuf + mt * 2048 + c * 128 + okl);
                khi[mt] = *(const bf16x8*)(kbuf + mt * 2048 + c * 128 + okh);
            }
        }
#pragma unroll
        for (int nt = 0; nt < 3; ++nt)
#pragma unroll
            for (int k2 = 0; k2 < 4; ++k2)
                if (k2 < mtw)
                    vf[nt][k2] = *(const bf16x4*)(vbuf + nt * 2048 + c * 128 +
                                                  (((k2 * 32) | (u * 8)) ^ mk));
        UNIT_DIAG(0);
    }

    // epilogue: deferred l-reduction, then O writeback
#pragma unroll
    for (int qs = 0; qs < 2; ++qs) {
        const int qt = qs ? qt1 : qt0;
#pragma unroll
        for (int g = 0; g < 2; ++g) {
            int h = hk * 4 + gp * 2 + g;
            float lt = l_s[qs][g];
            lt += __shfl_xor(lt, 16);
            lt += __shfl_xor(lt, 32);           // full sum for q=c, replicated
            float li = 1.0f / lt;
            float l0 = __shfl(li, 4 * u + 0);
            float l1 = __shfl(li, 4 * u + 1);
            float l2 = __shfl(li, 4 * u + 2);
            float l3 = __shfl(li, 4 * u + 3);
            float lr[4] = { l0, l1, l2, l3 };
#pragma unroll
            for (int nt = 0; nt < 3; ++nt)
#pragma unroll
                for (int r = 0; r < 4; ++r) {
                    int t = qt * 64 + 16 * w + 4 * u + r;
                    aob[((size_t)b * T_ + t) * NE_ + h * D_ + 16 * nt + c] =
                        f2bf(o[qs][g][nt][r] * lr[r]);
                }
        }
    }
}

// ---------------- kernel 3: out projection MFMA + bias ----------------
__global__ __launch_bounds__(256) void out_gemm_kernel(
    const short* __restrict__ aob, const short* __restrict__ wot,
    const float* __restrict__ bias, float* __restrict__ out)
{
    __shared__ __align__(16) char ldsb[49152];
    const int tid = threadIdx.x;
    const int n0 = blockIdx.x * 64;     // 6 tiles
    const int m0 = blockIdx.y * 128;    // 128 tiles
    const int lane = tid & 63, w = tid >> 6;
    const int c = lane & 15, u = lane >> 4;
    const int mo = (w & 1) * 64, no = (w >> 1) * 32;
    const int lrow = lane >> 3;
    const int lcol = (((lane & 7) ^ lrow) << 4);
    f32x4 acc[4][2] = {};

    auto stage = [&](int bsel, int t) {
        char* dst = ldsb + bsel * 24576;
        const char* Ag = (const char*)aob + (size_t)(m0 + w * 32 + lrow) * 768 + t * 128 + lcol;
#pragma unroll
        for (int p = 0; p < 4; ++p)
            gld16(Ag + p * 8 * 768, dst + w * 4096 + p * 1024);
        const char* Bg = (const char*)wot + (size_t)(n0 + w * 16 + lrow) * 768 + t * 128 + lcol;
#pragma unroll
        for (int p = 0; p < 2; ++p)
            gld16(Bg + p * 8 * 768, dst + 16384 + w * 2048 + p * 1024);
    };

    stage(0, 0);
    __syncthreads();
    int cur = 0;
#pragma unroll 1
    for (int t = 0; t < 6; ++t) {
        if (t < 5) stage(cur ^ 1, t + 1);
        const char* Ab = ldsb + cur * 24576;
        const char* Bb = Ab + 16384;
#pragma unroll
        for (int kk = 0; kk < 2; ++kk) {
            const int off = (kk * 64 + u * 16) ^ ((c & 7) << 4);
            bf16x8 af[4], bfr[2];
#pragma unroll
            for (int i = 0; i < 4; ++i)
                af[i] = *(const bf16x8*)(Ab + (mo + 16 * i + c) * 128 + off);
#pragma unroll
            for (int j = 0; j < 2; ++j)
                bfr[j] = *(const bf16x8*)(Bb + (no + 16 * j + c) * 128 + off);
#pragma unroll
            for (int i = 0; i < 4; ++i)
#pragma unroll
                for (int j = 0; j < 2; ++j)
                    acc[i][j] = __builtin_amdgcn_mfma_f32_16x16x32_bf16(af[i], bfr[j], acc[i][j], 0, 0, 0);
        }
        __syncthreads();
        cur ^= 1;
    }

#pragma unroll
    for (int i = 0; i < 4; ++i) {
#pragma unroll
        for (int j = 0; j < 2; ++j) {
            int n = n0 + no + 16 * j + c;
            int mb = m0 + mo + 16 * i + 4 * u;
            float bv = bias[n];
#pragma unroll
            for (int r = 0; r < 4; ++r)
                out[(size_t)(mb + r) * 384 + n] = acc[i][j][r] + bv;
        }
    }
}

// ---------------- launcher ----------------
extern "C" void kernel_launch(void* const* d_in, const int* in_sizes, int n_in,
                              void* d_out, int out_size, void* d_ws, size_t ws_size,
                              hipStream_t stream) {
    const float* x  = (const float*)d_in[0];
    const float* wq = (const float*)d_in[1];
    const float* wk = (const float*)d_in[2];
    const float* wv = (const float*)d_in[3];
    const float* wo = (const float*)d_in[4];
    const float* bo = (const float*)d_in[5];
    float* out = (float*)d_out;

    float* ct  = (float*)d_ws;                       // 49152 f32
    float* st  = ct + 49152;                         // 49152 f32
    short* xb  = (short*)(st + 49152);               // 16384*384
    short* wt  = xb  + (size_t)16384 * 384;          // 576*384
    short* wot = wt  + (size_t)576 * 384;            // 384*384
    short* qb  = wot + (size_t)384 * 384;            // 8*8*2048*64 (d-padded)
    short* kb  = qb  + (size_t)B_ * HQ_  * T_ * 64;  // 8*2*2048*64 (d-padded)
    short* vtb = kb  + (size_t)B_ * HKV_ * T_ * 64;  // 8*2*48*2048 (transposed)
    short* aob = vtb + (size_t)B_ * HKV_ * D_ * T_;  // 16384*384
    // total ~50.4 MB

    hipLaunchKernelGGL(prep_kernel, dim3(9056), dim3(256), 0, stream,
                       x, wq, wk, wv, wo, xb, wt, wot, ct, st, qb);
    hipLaunchKernelGGL(qkv_gemm_kernel, dim3(9, 128), dim3(256), 0, stream,
                       xb, wt, ct, st, qb, kb, vtb);
    hipLaunchKernelGGL(attn_kernel, dim3(16, 4, 8), dim3(256), 0, stream,
                       qb, kb, vtb, aob);
    hipLaunchKernelGGL(out_gemm_kernel, dim3(6, 128), dim3(256), 0, stream,
                       aob, wot, bo, out);
}